// Round 1
// baseline (771.727 us; speedup 1.0000x reference)
//
#include <hip/hip_runtime.h>

#define BB 4
#define CC 16
#define HH 256
#define WW 512
#define NHD 8
#define DD 32
#define TH 8
#define TW 32

// ---------------------------------------------------------------------------
// 3x3 same-padding conv, NCHW/OIHW, C_in=C_out=16, computing NC convs at once.
// Block: 256 threads = 8 rows x 32 cols tile, 1 pixel/thread, 16*NC outputs.
// Weights in LDS padded to 12 floats per (co,ci) so float4 broadcast reads are
// 16B-aligned. All weight reads are wave-uniform -> LDS broadcast.
// ---------------------------------------------------------------------------
template<int NC>
__global__ __launch_bounds__(256)
void conv3x3_kernel(const float* __restrict__ x,
                    const float* __restrict__ w0, const float* __restrict__ b0,
                    const float* __restrict__ w1, const float* __restrict__ b1,
                    const float* __restrict__ w2, const float* __restrict__ b2,
                    float* __restrict__ o0, float* __restrict__ o1, float* __restrict__ o2)
{
    __shared__ __align__(16) float xs[CC][TH+2][TW+2];
    __shared__ __align__(16) float wls[NC][CC][CC][12];
    __shared__ float bls[NC][CC];

    const int tid = threadIdx.x;
    const int bx = blockIdx.x, by = blockIdx.y, bz = blockIdx.z;

    const float* wg[3] = {w0, w1, w2};
    const float* bg[3] = {b0, b1, b2};
    #pragma unroll
    for (int cv = 0; cv < NC; ++cv) {
        for (int idx = tid; idx < CC*CC*9; idx += 256) {
            int co  = idx / (CC*9);
            int rem = idx - co*(CC*9);
            int ci  = rem / 9;
            int t   = rem - ci*9;
            wls[cv][co][ci][t] = wg[cv][idx];
        }
        if (tid < CC) bls[cv][tid] = bg[cv][tid];
    }

    // stage x tile (with 1-pixel halo, zero padded)
    const int row0 = by*TH - 1;
    const int col0 = bx*TW - 1;
    const float* xb = x + (size_t)bz*CC*HH*WW;
    for (int idx = tid; idx < CC*(TH+2)*(TW+2); idx += 256) {
        int ci  = idx / ((TH+2)*(TW+2));
        int rem = idx - ci*((TH+2)*(TW+2));
        int r   = rem / (TW+2);
        int cc2 = rem - r*(TW+2);
        int gr = row0 + r, gc = col0 + cc2;
        float val = 0.f;
        if (gr >= 0 && gr < HH && gc >= 0 && gc < WW)
            val = xb[(size_t)ci*HH*WW + gr*WW + gc];
        xs[ci][r][cc2] = val;
    }
    __syncthreads();

    const int c = tid & (TW-1);   // 0..31
    const int r = tid >> 5;       // 0..7

    float acc[NC*CC];
    #pragma unroll
    for (int cv = 0; cv < NC; ++cv)
        #pragma unroll
        for (int co = 0; co < CC; ++co)
            acc[cv*CC+co] = bls[cv][co];

    #pragma unroll 1
    for (int ci = 0; ci < CC; ++ci) {
        float xv[3][3];
        #pragma unroll
        for (int dy = 0; dy < 3; ++dy)
            #pragma unroll
            for (int dx = 0; dx < 3; ++dx)
                xv[dy][dx] = xs[ci][r+dy][c+dx];
        #pragma unroll
        for (int cv = 0; cv < NC; ++cv) {
            #pragma unroll
            for (int co = 0; co < CC; ++co) {
                const float4 wA = *reinterpret_cast<const float4*>(&wls[cv][co][ci][0]);
                const float4 wB = *reinterpret_cast<const float4*>(&wls[cv][co][ci][4]);
                const float w8  = wls[cv][co][ci][8];
                float a0 = acc[cv*CC+co];
                a0 += wA.x*xv[0][0];
                a0 += wA.y*xv[0][1];
                a0 += wA.z*xv[0][2];
                a0 += wA.w*xv[1][0];
                a0 += wB.x*xv[1][1];
                a0 += wB.y*xv[1][2];
                a0 += wB.z*xv[2][0];
                a0 += wB.w*xv[2][1];
                a0 += w8 *xv[2][2];
                acc[cv*CC+co] = a0;
            }
        }
    }

    const int gr = by*TH + r;
    const int gc = bx*TW + c;
    float* og[3] = {o0, o1, o2};
    #pragma unroll
    for (int cv = 0; cv < NC; ++cv)
        #pragma unroll
        for (int co = 0; co < CC; ++co)
            og[cv][((size_t)(bz*CC+co)*HH + gr)*WW + gc] = acc[cv*CC+co];
}

// ---------------------------------------------------------------------------
// Attention over the width axis. q/k/v in x-layout (b,c,h,w); per (b,c,head)
// slice: Q,K,V are (512 rows x 32 d), stored transposed (d-major).
// One thread = one query row; K/V rows are wave-uniform loads (contiguous
// 16-float runs -> s_load). Online softmax in exp2 domain. Output written via
// padded-LDS transpose for coalesced stores. a may alias q (each block reads
// only its own rows into registers before any global store).
// ---------------------------------------------------------------------------
__global__ __launch_bounds__(256)
void attn_kernel(const float* q,
                 const float* __restrict__ k,
                 const float* __restrict__ v,
                 float* a)
{
    __shared__ float tr[256][DD+1];

    const int blk  = blockIdx.x;     // 0..1023: (slice, half)
    const int s    = blk >> 1;
    const int half = blk & 1;
    const int n    = s & (NHD-1);
    const int bc   = s >> 3;
    const int hbase = bc*HH + n*DD;
    const int tid  = threadIdx.x;
    const int i0   = half*256;
    const int i    = i0 + tid;

    const float SC = 0.0625f * 1.44269504088896340736f;  // 1/sqrt(256) * log2(e)

    const float* qp = q + (size_t)hbase*WW + i;
    float qr[DD];
    #pragma unroll
    for (int dd = 0; dd < DD; ++dd) qr[dd] = qp[(size_t)dd*WW] * SC;

    const float* kp = k + (size_t)hbase*WW;
    const float* vp = v + (size_t)hbase*WW;

    float m = -1e30f, l = 0.f;
    float acc[DD];
    #pragma unroll
    for (int dd = 0; dd < DD; ++dd) acc[dd] = 0.f;

    #pragma unroll 1
    for (int j0 = 0; j0 < WW; j0 += 16) {
        float st[16];
        #pragma unroll
        for (int jj = 0; jj < 16; ++jj) st[jj] = 0.f;
        // QK^T: loads are wave-uniform, contiguous 16 floats per dd
        #pragma unroll
        for (int dd = 0; dd < DD; ++dd) {
            const float qv = qr[dd];
            #pragma unroll
            for (int jj = 0; jj < 16; ++jj)
                st[jj] += qv * kp[(size_t)dd*WW + j0 + jj];
        }
        float tmax = st[0];
        #pragma unroll
        for (int jj = 1; jj < 16; ++jj) tmax = fmaxf(tmax, st[jj]);
        const float mnew = fmaxf(m, tmax);
        const float corr = exp2f(m - mnew);
        m = mnew;
        l *= corr;
        #pragma unroll
        for (int dd = 0; dd < DD; ++dd) acc[dd] *= corr;
        #pragma unroll
        for (int jj = 0; jj < 16; ++jj) {
            const float p = exp2f(st[jj] - m);
            l += p;
            st[jj] = p;
        }
        // PV: same uniform-load pattern
        #pragma unroll
        for (int dd = 0; dd < DD; ++dd) {
            float t = acc[dd];
            #pragma unroll
            for (int jj = 0; jj < 16; ++jj)
                t += st[jj] * vp[(size_t)dd*WW + j0 + jj];
            acc[dd] = t;
        }
    }

    const float inv = 1.0f / l;
    #pragma unroll
    for (int dd = 0; dd < DD; ++dd) tr[tid][dd] = acc[dd] * inv;
    __syncthreads();

    float* ab = a + (size_t)hbase*WW + i0;
    #pragma unroll
    for (int it = 0; it < DD; ++it)
        ab[(size_t)it*WW + tid] = tr[tid][it];   // stride-33 LDS read: conflict-free
}

extern "C" void kernel_launch(void* const* d_in, const int* in_sizes, int n_in,
                              void* d_out, int out_size, void* d_ws, size_t ws_size,
                              hipStream_t stream) {
    (void)in_sizes; (void)n_in; (void)out_size; (void)ws_size;
    const float* x  = (const float*)d_in[0];
    const float* wq = (const float*)d_in[1];
    const float* bq = (const float*)d_in[2];
    const float* wk = (const float*)d_in[3];
    const float* bk = (const float*)d_in[4];
    const float* wv = (const float*)d_in[5];
    const float* bv = (const float*)d_in[6];
    const float* wo = (const float*)d_in[7];
    const float* bo = (const float*)d_in[8];
    float* out = (float*)d_out;

    const size_t S = (size_t)BB*CC*HH*WW;   // 8388608 elements per tensor
    float* q = (float*)d_ws;
    float* k = q + S;
    float* v = k + S;
    float* a = q;   // alias q: safe, see attn_kernel comment

    dim3 cgrid(WW/TW, HH/TH, BB);   // (16, 32, 4)
    conv3x3_kernel<3><<<cgrid, 256, 0, stream>>>(x, wq, bq, wk, bk, wv, bv, q, k, v);
    attn_kernel<<<dim3(1024), 256, 0, stream>>>(q, k, v, a);
    conv3x3_kernel<1><<<cgrid, 256, 0, stream>>>(a, wo, bo, wo, bo, wo, bo, out, out, out);
}

// Round 2
// 350.901 us; speedup vs baseline: 2.1993x; 2.1993x over previous
//
#include <hip/hip_runtime.h>

#define BB 4
#define CC 16
#define HH 256
#define WW 512
#define NHD 8
#define DD 32
#define TH 8
#define TW 32

typedef __attribute__((ext_vector_type(8))) short s8b;        // 8 bf16 (4 VGPRs)
typedef __attribute__((ext_vector_type(4))) float f32x4;
typedef __attribute__((ext_vector_type(4))) unsigned int u32x4;

__device__ inline unsigned short bf16r(float x) {
    unsigned u = __builtin_bit_cast(unsigned, x);
    unsigned r = (u + 0x7fffu + ((u >> 16) & 1u)) >> 16;
    return (unsigned short)r;
}
__device__ inline unsigned pk2(float lo, float hi) {
    return (unsigned)bf16r(lo) | ((unsigned)bf16r(hi) << 16);
}
__device__ inline f32x4 mfma16(u32x4 a, u32x4 b, f32x4 c) {
    return __builtin_amdgcn_mfma_f32_16x16x32_bf16(
        __builtin_bit_cast(s8b, a), __builtin_bit_cast(s8b, b), c, 0, 0, 0);
}

// ---------------------------------------------------------------------------
// 3x3 same-padding conv (unchanged from round 1 — reworked next round)
// ---------------------------------------------------------------------------
template<int NC>
__global__ __launch_bounds__(256)
void conv3x3_kernel(const float* __restrict__ x,
                    const float* __restrict__ w0, const float* __restrict__ b0,
                    const float* __restrict__ w1, const float* __restrict__ b1,
                    const float* __restrict__ w2, const float* __restrict__ b2,
                    float* __restrict__ o0, float* __restrict__ o1, float* __restrict__ o2)
{
    __shared__ __align__(16) float xs[CC][TH+2][TW+2];
    __shared__ __align__(16) float wls[NC][CC][CC][12];
    __shared__ float bls[NC][CC];

    const int tid = threadIdx.x;
    const int bx = blockIdx.x, by = blockIdx.y, bz = blockIdx.z;

    const float* wg[3] = {w0, w1, w2};
    const float* bg[3] = {b0, b1, b2};
    #pragma unroll
    for (int cv = 0; cv < NC; ++cv) {
        for (int idx = tid; idx < CC*CC*9; idx += 256) {
            int co  = idx / (CC*9);
            int rem = idx - co*(CC*9);
            int ci  = rem / 9;
            int t   = rem - ci*9;
            wls[cv][co][ci][t] = wg[cv][idx];
        }
        if (tid < CC) bls[cv][tid] = bg[cv][tid];
    }

    const int row0 = by*TH - 1;
    const int col0 = bx*TW - 1;
    const float* xb = x + (size_t)bz*CC*HH*WW;
    for (int idx = tid; idx < CC*(TH+2)*(TW+2); idx += 256) {
        int ci  = idx / ((TH+2)*(TW+2));
        int rem = idx - ci*((TH+2)*(TW+2));
        int r   = rem / (TW+2);
        int cc2 = rem - r*(TW+2);
        int gr = row0 + r, gc = col0 + cc2;
        float val = 0.f;
        if (gr >= 0 && gr < HH && gc >= 0 && gc < WW)
            val = xb[(size_t)ci*HH*WW + gr*WW + gc];
        xs[ci][r][cc2] = val;
    }
    __syncthreads();

    const int c = tid & (TW-1);
    const int r = tid >> 5;

    float acc[NC*CC];
    #pragma unroll
    for (int cv = 0; cv < NC; ++cv)
        #pragma unroll
        for (int co = 0; co < CC; ++co)
            acc[cv*CC+co] = bls[cv][co];

    #pragma unroll 1
    for (int ci = 0; ci < CC; ++ci) {
        float xv[3][3];
        #pragma unroll
        for (int dy = 0; dy < 3; ++dy)
            #pragma unroll
            for (int dx = 0; dx < 3; ++dx)
                xv[dy][dx] = xs[ci][r+dy][c+dx];
        #pragma unroll
        for (int cv = 0; cv < NC; ++cv) {
            #pragma unroll
            for (int co = 0; co < CC; ++co) {
                const float4 wA = *reinterpret_cast<const float4*>(&wls[cv][co][ci][0]);
                const float4 wB = *reinterpret_cast<const float4*>(&wls[cv][co][ci][4]);
                const float w8  = wls[cv][co][ci][8];
                float a0 = acc[cv*CC+co];
                a0 += wA.x*xv[0][0];
                a0 += wA.y*xv[0][1];
                a0 += wA.z*xv[0][2];
                a0 += wA.w*xv[1][0];
                a0 += wB.x*xv[1][1];
                a0 += wB.y*xv[1][2];
                a0 += wB.z*xv[2][0];
                a0 += wB.w*xv[2][1];
                a0 += w8 *xv[2][2];
                acc[cv*CC+co] = a0;
            }
        }
    }

    const int gr = by*TH + r;
    const int gc = bx*TW + c;
    float* og[3] = {o0, o1, o2};
    #pragma unroll
    for (int cv = 0; cv < NC; ++cv)
        #pragma unroll
        for (int co = 0; co < CC; ++co)
            og[cv][((size_t)(bz*CC+co)*HH + gr)*WW + gc] = acc[cv*CC+co];
}

// ---------------------------------------------------------------------------
// bf16 MFMA flash attention over the width axis.
// One block per (b,c,head) slice; 8 waves x 64 query rows.
// K staged [key][d] bf16, byte-swizzled ^((key&7)<<4)  -> conflict-free b128.
// V staged [d][key] bf16, byte-swizzled ^((d&7)<<4)    -> conflict-free b128.
// No-max softmax (|S| <= ~2 by construction), exp2 domain, l-normalize at end.
// P (64x32 per wave per tile) round-trips through a per-wave LDS buffer to
// convert D-fragment layout -> A-fragment layout.
// a aliases q: each wave reads only its own 64 rows into regs before writing.
// ---------------------------------------------------------------------------
__global__ __launch_bounds__(512)
void attn_mfma_kernel(const float* q,
                      const float* __restrict__ k,
                      const float* __restrict__ v,
                      float* a)
{
    __shared__ __align__(16) unsigned char Kl[WW*DD*2];      // 32 KiB
    __shared__ __align__(16) unsigned char Vl[DD*WW*2];      // 32 KiB
    __shared__ __align__(16) unsigned short Pl[8][16][40];   // 10 KiB

    const int s  = blockIdx.x;
    const int n  = s & (NHD-1);
    const int bc = s >> 3;
    const int hbase = bc*HH + n*DD;
    const float* qg = q + (size_t)hbase*WW;
    const float* kg = k + (size_t)hbase*WW;
    const float* vg = v + (size_t)hbase*WW;
    float* ag = a + (size_t)hbase*WW;

    const int tid = threadIdx.x;

    // --- stage K: thread t -> key = t, all 32 d, packed bf16 pairs ---
    {
        const int key = tid;
        unsigned pk[16];
        #pragma unroll
        for (int dp = 0; dp < 16; ++dp) {
            float lo = kg[(size_t)(2*dp)*WW + key];
            float hi = kg[(size_t)(2*dp+1)*WW + key];
            pk[dp] = pk2(lo, hi);
        }
        #pragma unroll
        for (int j = 0; j < 4; ++j) {
            unsigned off = (unsigned)(key*64 + j*16) ^ ((unsigned)(key&7) << 4);
            *(u32x4*)(Kl + off) = (u32x4){pk[4*j], pk[4*j+1], pk[4*j+2], pk[4*j+3]};
        }
    }
    // --- stage V: thread t -> d = t>>4, keys (t&15)*32 .. +31 ---
    {
        const int d  = tid >> 4;
        const int k0 = (tid & 15) * 32;
        float vv[32];
        #pragma unroll
        for (int j = 0; j < 8; ++j) {
            f32x4 t4 = *(const f32x4*)(vg + (size_t)d*WW + k0 + 4*j);
            vv[4*j+0] = t4[0]; vv[4*j+1] = t4[1]; vv[4*j+2] = t4[2]; vv[4*j+3] = t4[3];
        }
        unsigned pv[16];
        #pragma unroll
        for (int p = 0; p < 16; ++p) pv[p] = pk2(vv[2*p], vv[2*p+1]);
        #pragma unroll
        for (int j = 0; j < 4; ++j) {
            unsigned off = (unsigned)(d*1024 + k0*2 + j*16) ^ ((unsigned)(d&7) << 4);
            *(u32x4*)(Vl + off) = (u32x4){pv[4*j], pv[4*j+1], pv[4*j+2], pv[4*j+3]};
        }
    }

    // --- per-wave Q fragments (scale * log2e folded in) ---
    const int wid  = tid >> 6;
    const int lane = tid & 63;
    const int g = lane >> 4;
    const int r = lane & 15;
    const int w0 = wid * 64;
    const float SC = 0.0625f * 1.44269504088896340736f;

    u32x4 qf[4];
    #pragma unroll
    for (int rf = 0; rf < 4; ++rf) {
        const int row = w0 + rf*16 + r;
        unsigned pq[4];
        #pragma unroll
        for (int jj = 0; jj < 4; ++jj) {
            float lo = qg[(size_t)(8*g + 2*jj  )*WW + row] * SC;
            float hi = qg[(size_t)(8*g + 2*jj+1)*WW + row] * SC;
            pq[jj] = pk2(lo, hi);
        }
        qf[rf] = (u32x4){pq[0], pq[1], pq[2], pq[3]};
    }

    __syncthreads();   // K/V staged

    f32x4 oacc[4][2];
    float lsum[4][4];
    #pragma unroll
    for (int rf = 0; rf < 4; ++rf) {
        #pragma unroll
        for (int cf = 0; cf < 2; ++cf) oacc[rf][cf] = (f32x4){0.f,0.f,0.f,0.f};
        #pragma unroll
        for (int reg = 0; reg < 4; ++reg) lsum[rf][reg] = 0.f;
    }

    unsigned short* pw = &Pl[wid][0][0];
    const unsigned char* pr = (const unsigned char*)pw;

    #pragma unroll 1
    for (int j0 = 0; j0 < WW; j0 += 32) {
        // K B-fragments (cols = 16 keys each)
        u32x4 kf[2];
        #pragma unroll
        for (int cf = 0; cf < 2; ++cf) {
            const int key = j0 + cf*16 + r;
            unsigned off = (unsigned)(key*64 + g*16) ^ ((unsigned)(key&7) << 4);
            kf[cf] = *(const u32x4*)(Kl + off);
        }
        // V B-fragments (cols = 16 d each)
        u32x4 vf[2];
        #pragma unroll
        for (int cfd = 0; cfd < 2; ++cfd) {
            const int d = r + 16*cfd;
            unsigned off = (unsigned)(d*1024 + (j0 + 8*g)*2) ^ ((unsigned)(d&7) << 4);
            vf[cfd] = *(const u32x4*)(Vl + off);
        }

        // QK^T
        f32x4 sacc[4][2];
        #pragma unroll
        for (int rf = 0; rf < 4; ++rf) {
            sacc[rf][0] = mfma16(qf[rf], kf[0], (f32x4){0.f,0.f,0.f,0.f});
            sacc[rf][1] = mfma16(qf[rf], kf[1], (f32x4){0.f,0.f,0.f,0.f});
        }

        // softmax (no max subtraction) + P->bf16 round trip + PV, per row-frag
        #pragma unroll
        for (int rf = 0; rf < 4; ++rf) {
            float p0[4], p1[4];
            #pragma unroll
            for (int reg = 0; reg < 4; ++reg) {
                p0[reg] = exp2f(sacc[rf][0][reg]);
                p1[reg] = exp2f(sacc[rf][1][reg]);
                lsum[rf][reg] += p0[reg] + p1[reg];
            }
            #pragma unroll
            for (int reg = 0; reg < 4; ++reg) {
                pw[(4*g+reg)*40 + r     ] = bf16r(p0[reg]);
                pw[(4*g+reg)*40 + 16 + r] = bf16r(p1[reg]);
            }
            asm volatile("s_waitcnt lgkmcnt(0)" ::: "memory");
            u32x4 pa = *(const u32x4*)(pr + r*80 + g*16);
            oacc[rf][0] = mfma16(pa, vf[0], oacc[rf][0]);
            oacc[rf][1] = mfma16(pa, vf[1], oacc[rf][1]);
        }
    }

    // reduce l across the 16 lanes holding the same rows, invert
    #pragma unroll
    for (int rf = 0; rf < 4; ++rf)
        #pragma unroll
        for (int reg = 0; reg < 4; ++reg) {
            float t = lsum[rf][reg];
            t += __shfl_xor(t, 1);
            t += __shfl_xor(t, 2);
            t += __shfl_xor(t, 4);
            t += __shfl_xor(t, 8);
            lsum[rf][reg] = 1.0f / t;
        }

    // store: reg axis = 4 consecutive rows -> float4 stores
    #pragma unroll
    for (int rf = 0; rf < 4; ++rf)
        #pragma unroll
        for (int cfd = 0; cfd < 2; ++cfd) {
            const int d = r + 16*cfd;
            f32x4 o = oacc[rf][cfd];
            o[0] *= lsum[rf][0];
            o[1] *= lsum[rf][1];
            o[2] *= lsum[rf][2];
            o[3] *= lsum[rf][3];
            *(f32x4*)(ag + (size_t)d*WW + (w0 + rf*16 + 4*g)) = o;
        }
}

extern "C" void kernel_launch(void* const* d_in, const int* in_sizes, int n_in,
                              void* d_out, int out_size, void* d_ws, size_t ws_size,
                              hipStream_t stream) {
    (void)in_sizes; (void)n_in; (void)out_size; (void)ws_size;
    const float* x  = (const float*)d_in[0];
    const float* wq = (const float*)d_in[1];
    const float* bq = (const float*)d_in[2];
    const float* wk = (const float*)d_in[3];
    const float* bk = (const float*)d_in[4];
    const float* wv = (const float*)d_in[5];
    const float* bv = (const float*)d_in[6];
    const float* wo = (const float*)d_in[7];
    const float* bo = (const float*)d_in[8];
    float* out = (float*)d_out;

    const size_t S = (size_t)BB*CC*HH*WW;
    float* q = (float*)d_ws;
    float* k = q + S;
    float* v = k + S;
    float* a = q;   // alias q: safe (per-wave row ownership)

    dim3 cgrid(WW/TW, HH/TH, BB);
    conv3x3_kernel<3><<<cgrid, 256, 0, stream>>>(x, wq, bq, wk, bk, wv, bv, q, k, v);
    attn_mfma_kernel<<<dim3(512), 512, 0, stream>>>(q, k, v, a);
    conv3x3_kernel<1><<<cgrid, 256, 0, stream>>>(a, wo, bo, wo, bo, wo, bo, out, out, out);
}

// Round 3
// 158.422 us; speedup vs baseline: 4.8713x; 2.2150x over previous
//
#include <hip/hip_runtime.h>

#define BB 4
#define CC 16
#define HH 256
#define WW 512
#define NHD 8
#define DD 32

typedef __attribute__((ext_vector_type(8))) short s8b;        // 8 bf16 (4 VGPRs)
typedef __attribute__((ext_vector_type(4))) float f32x4;
typedef __attribute__((ext_vector_type(4))) unsigned int u32x4;

__device__ inline unsigned short bf16r(float x) {
    unsigned u = __builtin_bit_cast(unsigned, x);
    unsigned r = (u + 0x7fffu + ((u >> 16) & 1u)) >> 16;
    return (unsigned short)r;
}
__device__ inline unsigned pk2(float lo, float hi) {
    return (unsigned)bf16r(lo) | ((unsigned)bf16r(hi) << 16);
}
// hi/lo split of two floats -> packed bf16 pairs (hi word = second element)
__device__ inline void split2(float a, float b, unsigned& hi, unsigned& lo) {
    unsigned short ha = bf16r(a), hb = bf16r(b);
    float fa = __builtin_bit_cast(float, (unsigned)ha << 16);
    float fb = __builtin_bit_cast(float, (unsigned)hb << 16);
    hi = (unsigned)ha | ((unsigned)hb << 16);
    lo = (unsigned)bf16r(a - fa) | ((unsigned)bf16r(b - fb) << 16);
}
__device__ inline f32x4 mfma16(u32x4 a, u32x4 b, f32x4 c) {
    return __builtin_amdgcn_mfma_f32_16x16x32_bf16(
        __builtin_bit_cast(s8b, a), __builtin_bit_cast(s8b, b), c, 0, 0, 0);
}

// ---------------------------------------------------------------------------
// bf16-MFMA implicit-GEMM 3x3 conv, 3-term precision split (wh*xh+wl*xh+wh*xl).
// K-dim = 10 taps x 16 ci = 160 -> 5 MFMAs of K=32 (tap 9 zero-padded in A).
// x staged channel-last in LDS (hi/lo), XOR-swizzled: B-frag = 1 ds_read_b128.
// Weights as A-fragments in registers. Block 256 thr = 4 waves, tile 8h x 64w.
// OUT_BF16: bf16 planar out via per-wave LDS transpose (128B-coalesced).
// else:     fp32 planar out, direct stores.
// ---------------------------------------------------------------------------
template<int NC, bool OUT_BF16>
__global__ __launch_bounds__(256)
void conv_mfma_kernel(const float* __restrict__ x,
                      const float* __restrict__ w0, const float* __restrict__ b0,
                      const float* __restrict__ w1, const float* __restrict__ b1,
                      const float* __restrict__ w2, const float* __restrict__ b2,
                      void* o0v, void* o1v, void* o2v)
{
    constexpr int LROWS = 10, LCOLS = 66, NPX = LROWS*LCOLS; // 660
    __shared__ __align__(16) unsigned char xs_hi[NPX*32];    // 21120 B
    __shared__ __align__(16) unsigned char xs_lo[NPX*32];
    __shared__ __align__(16) unsigned short obuf[OUT_BF16 ? 4*NC*16*72 : 64];

    const int tid = threadIdx.x;
    const int bx = blockIdx.x, by = blockIdx.y, bz = blockIdx.z;
    const int lane = tid & 63, wid = tid >> 6;
    const int g = lane >> 4, r = lane & 15;

    // --- build weight A-fragments in registers (hi & lo) ---
    const float* wg[3] = {w0, w1, w2};
    const float* bg[3] = {b0, b1, b2};
    u32x4 wh[NC][5], wl[NC][5];
    #pragma unroll
    for (int cv = 0; cv < NC; ++cv) {
        #pragma unroll
        for (int kg = 0; kg < 5; ++kg) {
            int tap = 2*kg + (g >> 1);           // k = tap*16 + ci
            unsigned hi4[4], lo4[4];
            #pragma unroll
            for (int p = 0; p < 4; ++p) {
                float e0 = 0.f, e1 = 0.f;
                if (tap < 9) {
                    int ci0 = (g & 1)*8 + 2*p;
                    e0 = wg[cv][(r*CC + ci0    )*9 + tap];
                    e1 = wg[cv][(r*CC + ci0 + 1)*9 + tap];
                }
                split2(e0, e1, hi4[p], lo4[p]);
            }
            wh[cv][kg] = (u32x4){hi4[0], hi4[1], hi4[2], hi4[3]};
            wl[cv][kg] = (u32x4){lo4[0], lo4[1], lo4[2], lo4[3]};
        }
    }
    float bias_[NC][4];
    #pragma unroll
    for (int cv = 0; cv < NC; ++cv)
        #pragma unroll
        for (int reg = 0; reg < 4; ++reg)
            bias_[cv][reg] = bg[cv][4*g + reg];

    // --- stage x tile channel-last hi/lo (halo, zero-padded) ---
    const int row0 = by*8 - 1;
    const int col0 = bx*64 - 1;
    const float* xb = x + (size_t)bz*CC*HH*WW;
    for (int idx = tid; idx < NPX; idx += 256) {
        int rr = idx / LCOLS, cc2 = idx - rr*LCOLS;
        int gr = row0 + rr, gc = col0 + cc2;
        bool ok = (gr >= 0) & (gr < HH) & (gc >= 0) & (gc < WW);
        const float* px = xb + (size_t)gr*WW + gc;
        unsigned hi[8], lo[8];
        #pragma unroll
        for (int cp = 0; cp < 8; ++cp) {
            float a_ = ok ? px[(size_t)(2*cp  )*HH*WW] : 0.f;
            float b_ = ok ? px[(size_t)(2*cp+1)*HH*WW] : 0.f;
            split2(a_, b_, hi[cp], lo[cp]);
        }
        unsigned swz = (unsigned)((idx & 4) << 2);
        unsigned off0 = ((unsigned)idx*32     ) ^ swz;
        unsigned off1 = ((unsigned)idx*32 + 16) ^ swz;
        *(u32x4*)(xs_hi + off0) = (u32x4){hi[0], hi[1], hi[2], hi[3]};
        *(u32x4*)(xs_hi + off1) = (u32x4){hi[4], hi[5], hi[6], hi[7]};
        *(u32x4*)(xs_lo + off0) = (u32x4){lo[0], lo[1], lo[2], lo[3]};
        *(u32x4*)(xs_lo + off1) = (u32x4){lo[4], lo[5], lo[6], lo[7]};
    }
    __syncthreads();

    // per-lane constant parts of the B-frag address
    int pk_base[5];
    #pragma unroll
    for (int kg = 0; kg < 5; ++kg) {
        int tap = 2*kg + (g >> 1);
        if (tap > 8) tap = 8;                    // A is zero there; any valid addr
        pk_base[kg] = (tap/3)*LCOLS + (tap%3) + r;
    }
    const unsigned hoff = (unsigned)((g & 1) * 16);

    // --- main: each wave does rows {2*wid, 2*wid+1}, 4 w-tiles each ---
    #pragma unroll 1
    for (int hh = 0; hh < 2; ++hh) {
        const int hb = wid*2 + hh;
        #pragma unroll 1
        for (int wt = 0; wt < 4; ++wt) {
            const int tbase = hb*LCOLS + wt*16;
            u32x4 Bh[5], Bl[5];
            #pragma unroll
            for (int kg = 0; kg < 5; ++kg) {
                int px = tbase + pk_base[kg];
                unsigned off = (((unsigned)px << 5) + hoff) ^ (unsigned)((px & 4) << 2);
                Bh[kg] = *(const u32x4*)(xs_hi + off);
                Bl[kg] = *(const u32x4*)(xs_lo + off);
            }
            f32x4 acc[NC];
            #pragma unroll
            for (int cv = 0; cv < NC; ++cv) acc[cv] = (f32x4){0.f,0.f,0.f,0.f};
            #pragma unroll
            for (int kg = 0; kg < 5; ++kg)
                #pragma unroll
                for (int cv = 0; cv < NC; ++cv) {
                    acc[cv] = mfma16(wh[cv][kg], Bh[kg], acc[cv]);
                    acc[cv] = mfma16(wl[cv][kg], Bh[kg], acc[cv]);
                    acc[cv] = mfma16(wh[cv][kg], Bl[kg], acc[cv]);
                }
            // D layout: col(lane&15)=pixel(r), row(4g+reg)=co
            if constexpr (OUT_BF16) {
                #pragma unroll
                for (int cv = 0; cv < NC; ++cv)
                    #pragma unroll
                    for (int reg = 0; reg < 4; ++reg)
                        obuf[(((wid*NC + cv)*16) + 4*g + reg)*72 + wt*16 + r] =
                            bf16r(acc[cv][reg] + bias_[cv][reg]);
            } else {
                float* o0 = (float*)o0v;
                #pragma unroll
                for (int reg = 0; reg < 4; ++reg)
                    o0[((size_t)(bz*CC + 4*g + reg)*HH + (by*8 + hb))*WW
                       + bx*64 + wt*16 + r] = acc[0][reg] + bias_[0][reg];
            }
        }
        if constexpr (OUT_BF16) {
            // per-wave coalesced store of this h-row: NC*16 rows x 64 w (bf16)
            #pragma unroll
            for (int it = 0; it < NC*2; ++it) {
                int slot = it*64 + lane;          // (cv*16+co)*8 + w8
                int rowi = slot >> 3;
                int w8   = slot & 7;
                int cv   = rowi >> 4, co = rowi & 15;
                u32x4 d4 = *(const u32x4*)(&obuf[((wid*NC*16) + rowi)*72 + w8*8]);
                unsigned short* op = (unsigned short*)(cv == 0 ? o0v : (cv == 1 ? o1v : o2v));
                *(u32x4*)(op + ((size_t)(bz*CC + co)*HH + (by*8 + hb))*WW
                               + bx*64 + w8*8) = d4;
            }
        }
    }
}

// ---------------------------------------------------------------------------
// bf16 MFMA flash attention over the width axis (inputs now bf16 planar).
// One block per (b,c,head) slice; 8 waves x 64 query rows.
// Scale*log2e applied to scores post-MFMA (Q packed raw).
// ---------------------------------------------------------------------------
__global__ __launch_bounds__(512)
void attn_mfma_kernel(const unsigned short* __restrict__ q,
                      const unsigned short* __restrict__ k,
                      const unsigned short* __restrict__ v,
                      float* __restrict__ a)
{
    __shared__ __align__(16) unsigned char Kl[WW*DD*2];      // 32 KiB
    __shared__ __align__(16) unsigned char Vl[DD*WW*2];      // 32 KiB
    __shared__ __align__(16) unsigned short Pl[8][16][40];   // 10 KiB

    const int s  = blockIdx.x;
    const int n  = s & (NHD-1);
    const int bc = s >> 3;
    const int hbase = bc*HH + n*DD;
    const unsigned short* qg = q + (size_t)hbase*WW;
    const unsigned short* kg = k + (size_t)hbase*WW;
    const unsigned short* vg = v + (size_t)hbase*WW;
    float* ag = a + (size_t)hbase*WW;

    const int tid = threadIdx.x;

    // --- stage K: thread t -> key = t, all 32 d, bf16 pairs along d ---
    {
        const int key = tid;
        unsigned pk[16];
        #pragma unroll
        for (int dp = 0; dp < 16; ++dp)
            pk[dp] = (unsigned)kg[(size_t)(2*dp)*WW + key]
                   | ((unsigned)kg[(size_t)(2*dp+1)*WW + key] << 16);
        #pragma unroll
        for (int j = 0; j < 4; ++j) {
            unsigned off = (unsigned)(key*64 + j*16) ^ ((unsigned)(key&7) << 4);
            *(u32x4*)(Kl + off) = (u32x4){pk[4*j], pk[4*j+1], pk[4*j+2], pk[4*j+3]};
        }
    }
    // --- stage V: thread t -> d = t>>4, keys (t&15)*32..+31 (pairs native) ---
    {
        const int d  = tid >> 4;
        const int k0 = (tid & 15) * 32;
        const unsigned short* vrow = vg + (size_t)d*WW + k0;
        #pragma unroll
        for (int j = 0; j < 4; ++j) {
            u32x4 t4 = *(const u32x4*)(vrow + 8*j);
            unsigned off = (unsigned)(d*1024 + k0*2 + j*16) ^ ((unsigned)(d&7) << 4);
            *(u32x4*)(Vl + off) = t4;
        }
    }

    // --- per-wave Q fragments (raw bf16) ---
    const int wid  = tid >> 6;
    const int lane = tid & 63;
    const int g = lane >> 4;
    const int r = lane & 15;
    const int w0 = wid * 64;
    const float SC = 0.0625f * 1.44269504088896340736f;  // 1/sqrt(256) * log2(e)

    u32x4 qf[4];
    #pragma unroll
    for (int rf = 0; rf < 4; ++rf) {
        const int row = w0 + rf*16 + r;
        unsigned pq[4];
        #pragma unroll
        for (int jj = 0; jj < 4; ++jj)
            pq[jj] = (unsigned)qg[(size_t)(8*g + 2*jj)*WW + row]
                   | ((unsigned)qg[(size_t)(8*g + 2*jj+1)*WW + row] << 16);
        qf[rf] = (u32x4){pq[0], pq[1], pq[2], pq[3]};
    }

    __syncthreads();   // K/V staged

    f32x4 oacc[4][2];
    float lsum[4][4];
    #pragma unroll
    for (int rf = 0; rf < 4; ++rf) {
        #pragma unroll
        for (int cf = 0; cf < 2; ++cf) oacc[rf][cf] = (f32x4){0.f,0.f,0.f,0.f};
        #pragma unroll
        for (int reg = 0; reg < 4; ++reg) lsum[rf][reg] = 0.f;
    }

    unsigned short* pw = &Pl[wid][0][0];
    const unsigned char* pr = (const unsigned char*)pw;

    #pragma unroll 1
    for (int j0 = 0; j0 < WW; j0 += 32) {
        u32x4 kf[2];
        #pragma unroll
        for (int cf = 0; cf < 2; ++cf) {
            const int key = j0 + cf*16 + r;
            unsigned off = (unsigned)(key*64 + g*16) ^ ((unsigned)(key&7) << 4);
            kf[cf] = *(const u32x4*)(Kl + off);
        }
        u32x4 vf[2];
        #pragma unroll
        for (int cfd = 0; cfd < 2; ++cfd) {
            const int d = r + 16*cfd;
            unsigned off = (unsigned)(d*1024 + (j0 + 8*g)*2) ^ ((unsigned)(d&7) << 4);
            vf[cfd] = *(const u32x4*)(Vl + off);
        }

        f32x4 sacc[4][2];
        #pragma unroll
        for (int rf = 0; rf < 4; ++rf) {
            sacc[rf][0] = mfma16(qf[rf], kf[0], (f32x4){0.f,0.f,0.f,0.f});
            sacc[rf][1] = mfma16(qf[rf], kf[1], (f32x4){0.f,0.f,0.f,0.f});
        }

        #pragma unroll
        for (int rf = 0; rf < 4; ++rf) {
            float p0[4], p1[4];
            #pragma unroll
            for (int reg = 0; reg < 4; ++reg) {
                p0[reg] = exp2f(sacc[rf][0][reg] * SC);
                p1[reg] = exp2f(sacc[rf][1][reg] * SC);
                lsum[rf][reg] += p0[reg] + p1[reg];
            }
            #pragma unroll
            for (int reg = 0; reg < 4; ++reg) {
                pw[(4*g+reg)*40 + r     ] = bf16r(p0[reg]);
                pw[(4*g+reg)*40 + 16 + r] = bf16r(p1[reg]);
            }
            asm volatile("s_waitcnt lgkmcnt(0)" ::: "memory");
            u32x4 pa = *(const u32x4*)(pr + r*80 + g*16);
            oacc[rf][0] = mfma16(pa, vf[0], oacc[rf][0]);
            oacc[rf][1] = mfma16(pa, vf[1], oacc[rf][1]);
        }
    }

    #pragma unroll
    for (int rf = 0; rf < 4; ++rf)
        #pragma unroll
        for (int reg = 0; reg < 4; ++reg) {
            float t = lsum[rf][reg];
            t += __shfl_xor(t, 1);
            t += __shfl_xor(t, 2);
            t += __shfl_xor(t, 4);
            t += __shfl_xor(t, 8);
            lsum[rf][reg] = 1.0f / t;
        }

    #pragma unroll
    for (int rf = 0; rf < 4; ++rf)
        #pragma unroll
        for (int cfd = 0; cfd < 2; ++cfd) {
            const int d = r + 16*cfd;
            f32x4 o = oacc[rf][cfd];
            o[0] *= lsum[rf][0];
            o[1] *= lsum[rf][1];
            o[2] *= lsum[rf][2];
            o[3] *= lsum[rf][3];
            *(f32x4*)(ag + (size_t)d*WW + (w0 + rf*16 + 4*g)) = o;
        }
}

extern "C" void kernel_launch(void* const* d_in, const int* in_sizes, int n_in,
                              void* d_out, int out_size, void* d_ws, size_t ws_size,
                              hipStream_t stream) {
    (void)in_sizes; (void)n_in; (void)out_size; (void)ws_size;
    const float* x  = (const float*)d_in[0];
    const float* wq = (const float*)d_in[1];
    const float* bq = (const float*)d_in[2];
    const float* wk = (const float*)d_in[3];
    const float* bk = (const float*)d_in[4];
    const float* wv = (const float*)d_in[5];
    const float* bv = (const float*)d_in[6];
    const float* wo = (const float*)d_in[7];
    const float* bo = (const float*)d_in[8];
    float* out = (float*)d_out;

    const size_t S = (size_t)BB*CC*HH*WW;        // 8388608
    float* a = (float*)d_ws;                      // S floats   (33.5 MB)
    unsigned short* q = (unsigned short*)(a + S); // S bf16     (16.8 MB)
    unsigned short* k = q + S;
    unsigned short* v = k + S;

    dim3 cgrid(WW/64, HH/8, BB);   // (8, 32, 4)
    conv_mfma_kernel<3, true ><<<cgrid, 256, 0, stream>>>(x, wq, bq, wk, bk, wv, bv, q, k, v);
    attn_mfma_kernel<<<dim3(512), 512, 0, stream>>>(q, k, v, a);
    conv_mfma_kernel<1, false><<<cgrid, 256, 0, stream>>>(a, wo, bo, wo, bo, wo, bo, out, out, out);
}

// Round 4
// 120.526 us; speedup vs baseline: 6.4030x; 1.3144x over previous
//
#include <hip/hip_runtime.h>

#define BB 4
#define CC 16
#define HH 256
#define WW 512
#define NHD 8
#define DD 32

typedef __attribute__((ext_vector_type(8))) short s8b;        // 8 bf16 (4 VGPRs)
typedef __attribute__((ext_vector_type(4))) float f32x4;
typedef __attribute__((ext_vector_type(4))) unsigned int u32x4;

__device__ inline unsigned cvtpk(float a, float b) {          // (lo=a, hi=b) bf16 RNE
    unsigned r;
    asm("v_cvt_pk_bf16_f32 %0, %1, %2" : "=v"(r) : "v"(a), "v"(b));
    return r;
}
__device__ inline unsigned short bf16r(float x) {
    unsigned u = __builtin_bit_cast(unsigned, x);
    unsigned r = (u + 0x7fffu + ((u >> 16) & 1u)) >> 16;
    return (unsigned short)r;
}
__device__ inline f32x4 mfma16(u32x4 a, u32x4 b, f32x4 c) {
    return __builtin_amdgcn_mfma_f32_16x16x32_bf16(
        __builtin_bit_cast(s8b, a), __builtin_bit_cast(s8b, b), c, 0, 0, 0);
}

// ---------------------------------------------------------------------------
// Setup: build bf16 hi/lo weight A-fragments for all 4 convs (q,k,v,o).
// Layout: wfrag u32[ ((plane*4+cv)*5+kg)*64 + lane ][4]  (16B per lane).
// A row = co (lane&15); k = tap*16+ci, lane g covers k 8g..8g+7 of each K=32.
// ---------------------------------------------------------------------------
__global__ __launch_bounds__(64)
void wsetup_kernel(const float* __restrict__ w0, const float* __restrict__ w1,
                   const float* __restrict__ w2, const float* __restrict__ w3,
                   unsigned* __restrict__ wfrag)
{
    const int lane = threadIdx.x;
    const int cv = blockIdx.x;
    const float* wg[4] = {w0, w1, w2, w3};
    const int r = lane & 15, g = lane >> 4;
    const int ci0 = (g & 1) * 8;
    #pragma unroll
    for (int kg = 0; kg < 5; ++kg) {
        int tap = 2*kg + (g >> 1);
        unsigned hi[4], lo[4];
        #pragma unroll
        for (int j = 0; j < 4; ++j) {
            float e0 = 0.f, e1 = 0.f;
            if (tap < 9) {
                e0 = wg[cv][(r*CC + ci0 + 2*j    )*9 + tap];
                e1 = wg[cv][(r*CC + ci0 + 2*j + 1)*9 + tap];
            }
            unsigned h = cvtpk(e0, e1);
            float f0 = __builtin_bit_cast(float, h << 16);
            float f1 = __builtin_bit_cast(float, h & 0xffff0000u);
            hi[j] = h;
            lo[j] = cvtpk(e0 - f0, e1 - f1);
        }
        *(u32x4*)(wfrag + (size_t)(((0*4 + cv)*5 + kg)*64 + lane)*4) =
            (u32x4){hi[0], hi[1], hi[2], hi[3]};
        *(u32x4*)(wfrag + (size_t)(((1*4 + cv)*5 + kg)*64 + lane)*4) =
            (u32x4){lo[0], lo[1], lo[2], lo[3]};
    }
}

// ---------------------------------------------------------------------------
// bf16-MFMA implicit-GEMM 3x3 conv, 3-term split (wh*xh + wl*xh + wh*xl).
// Tile 16h x 32w, 4 waves (each: 4 h-rows x 2 w-tiles). LDS 38.25 KiB:
// [px][hi0 hi1 lo0 lo1] 16B slots, slot-swizzled s^=(px&3) (<=2-way conflicts).
// Weight frags loaded from precomputed global (issued before staging).
// PAIRED: outputs 3 tensors, bf16 h-paired u32 [c][h/2][w] (for attn).
// else:   fp32 planar [c][h][w] to d_out.
// ---------------------------------------------------------------------------
template<int NC, int CVB, bool PAIRED>
__global__ __launch_bounds__(256)
void conv_mfma_kernel(const float* __restrict__ x,
                      const unsigned* __restrict__ wfrag,
                      const float* __restrict__ b0, const float* __restrict__ b1,
                      const float* __restrict__ b2,
                      unsigned* __restrict__ o0, unsigned* __restrict__ o1,
                      unsigned* __restrict__ o2, float* __restrict__ of)
{
    constexpr int LC2 = 34, NPX = 18*34;                  // 612 pixels w/ halo
    __shared__ __align__(16) unsigned char xs[NPX*64];

    const int tid = threadIdx.x;
    const int bx = blockIdx.x, by = blockIdx.y, bz = blockIdx.z;
    const int lane = tid & 63, wid = tid >> 6;
    const int g = lane >> 4, r = lane & 15;

    // weight-fragment loads: issued first, consumed after the barrier
    u32x4 wh[NC][5], wl[NC][5];
    #pragma unroll
    for (int cv = 0; cv < NC; ++cv)
        #pragma unroll
        for (int kg = 0; kg < 5; ++kg) {
            wh[cv][kg] = *(const u32x4*)(wfrag + (size_t)(((CVB+cv)*5 + kg)*64 + lane)*4);
            wl[cv][kg] = *(const u32x4*)(wfrag + (size_t)(((4+CVB+cv)*5 + kg)*64 + lane)*4);
        }
    const float* bg[3] = {b0, b1, b2};
    f32x4 bias[NC];
    #pragma unroll
    for (int cv = 0; cv < NC; ++cv) bias[cv] = *(const f32x4*)(bg[cv] + 4*g);

    // stage x: per pixel, 16 channels -> hi/lo bf16-pair slots
    const int row0 = by*16 - 1, col0 = bx*32 - 1;
    const float* xb = x + (size_t)bz*CC*HH*WW;
    for (int idx = tid; idx < NPX; idx += 256) {
        int rr = idx / LC2, cc2 = idx - rr*LC2;
        int gr = row0 + rr, gc = col0 + cc2;
        bool ok = (gr >= 0) & (gr < HH) & (gc >= 0) & (gc < WW);
        const float* px = xb + (size_t)gr*WW + gc;
        float v0[16];
        #pragma unroll
        for (int c8 = 0; c8 < 16; ++c8) v0[c8] = ok ? px[(size_t)c8*HH*WW] : 0.f;
        unsigned hi[8], lo[8];
        #pragma unroll
        for (int p = 0; p < 8; ++p) {
            unsigned h = cvtpk(v0[2*p], v0[2*p+1]);
            float f0 = __builtin_bit_cast(float, h << 16);
            float f1 = __builtin_bit_cast(float, h & 0xffff0000u);
            hi[p] = h;
            lo[p] = cvtpk(v0[2*p] - f0, v0[2*p+1] - f1);
        }
        unsigned base = (unsigned)idx*64, m = ((unsigned)idx & 3) << 4;
        *(u32x4*)(xs + base + (( 0u) ^ m)) = (u32x4){hi[0], hi[1], hi[2], hi[3]};
        *(u32x4*)(xs + base + ((16u) ^ m)) = (u32x4){hi[4], hi[5], hi[6], hi[7]};
        *(u32x4*)(xs + base + ((32u) ^ m)) = (u32x4){lo[0], lo[1], lo[2], lo[3]};
        *(u32x4*)(xs + base + ((48u) ^ m)) = (u32x4){lo[4], lo[5], lo[6], lo[7]};
    }
    __syncthreads();

    int pk_base[5];
    #pragma unroll
    for (int kg = 0; kg < 5; ++kg) {
        int tap = 2*kg + (g >> 1);
        if (tap > 8) tap = 8;                 // A-frag is zero there
        pk_base[kg] = (tap/3)*LC2 + (tap%3) + r;
    }
    const unsigned sh = (unsigned)(g & 1) << 4;   // hi slot; lo slot = sh|32

    auto tile = [&](int hr, int wt, f32x4* acc) {
        const int tb = hr*LC2 + wt*16;
        #pragma unroll
        for (int kg = 0; kg < 5; ++kg) {
            int px = tb + pk_base[kg];
            unsigned b_ = (unsigned)px*64, m = ((unsigned)px & 3) << 4;
            u32x4 Bh = *(const u32x4*)(xs + b_ + ( sh        ^ m));
            u32x4 Bl = *(const u32x4*)(xs + b_ + ((sh | 32u) ^ m));
            #pragma unroll
            for (int cv = 0; cv < NC; ++cv) {
                acc[cv] = mfma16(wh[cv][kg], Bh, acc[cv]);
                acc[cv] = mfma16(wl[cv][kg], Bh, acc[cv]);
                acc[cv] = mfma16(wh[cv][kg], Bl, acc[cv]);
            }
        }
    };

    #pragma unroll 1
    for (int hp = 0; hp < 2; ++hp) {
        const int hrE = 4*wid + 2*hp;
        #pragma unroll 1
        for (int wt = 0; wt < 2; ++wt) {
            const int col = bx*32 + wt*16 + r;
            if constexpr (PAIRED) {
                f32x4 aE[NC];
                #pragma unroll
                for (int cv = 0; cv < NC; ++cv) aE[cv] = (f32x4){0.f,0.f,0.f,0.f};
                tile(hrE, wt, aE);
                unsigned Ep[NC][2];
                #pragma unroll
                for (int cv = 0; cv < NC; ++cv) {
                    Ep[cv][0] = cvtpk(aE[cv][0] + bias[cv][0], aE[cv][1] + bias[cv][1]);
                    Ep[cv][1] = cvtpk(aE[cv][2] + bias[cv][2], aE[cv][3] + bias[cv][3]);
                }
                f32x4 aO[NC];
                #pragma unroll
                for (int cv = 0; cv < NC; ++cv) aO[cv] = (f32x4){0.f,0.f,0.f,0.f};
                tile(hrE + 1, wt, aO);
                const int hpix = by*8 + 2*wid + hp;
                #pragma unroll
                for (int cv = 0; cv < NC; ++cv) {
                    unsigned Op0 = cvtpk(aO[cv][0] + bias[cv][0], aO[cv][1] + bias[cv][1]);
                    unsigned Op1 = cvtpk(aO[cv][2] + bias[cv][2], aO[cv][3] + bias[cv][3]);
                    unsigned wd[4] = {
                        __builtin_amdgcn_perm(Op0, Ep[cv][0], 0x05040100u),
                        __builtin_amdgcn_perm(Op0, Ep[cv][0], 0x07060302u),
                        __builtin_amdgcn_perm(Op1, Ep[cv][1], 0x05040100u),
                        __builtin_amdgcn_perm(Op1, Ep[cv][1], 0x07060302u) };
                    unsigned* op = (cv == 0) ? o0 : (cv == 1) ? o1 : o2;
                    #pragma unroll
                    for (int reg = 0; reg < 4; ++reg)
                        op[((size_t)(bz*CC + 4*g + reg)*(HH/2) + hpix)*WW + col] = wd[reg];
                }
            } else {
                #pragma unroll 1
                for (int e = 0; e < 2; ++e) {
                    f32x4 a0[1] = {(f32x4){0.f,0.f,0.f,0.f}};
                    tile(hrE + e, wt, a0);
                    const int h = by*16 + hrE + e;
                    #pragma unroll
                    for (int reg = 0; reg < 4; ++reg)
                        of[((size_t)(bz*CC + 4*g + reg)*HH + h)*WW + col] =
                            a0[0][reg] + bias[0][reg];
                }
            }
        }
    }
}

// ---------------------------------------------------------------------------
// bf16 MFMA flash attention over the width axis; q/k/v are h-paired u32 bf16
// tensors [c][h/2][w]. One block per (b,c,head) slice; 8 waves x 64 q-rows.
// ---------------------------------------------------------------------------
__global__ __launch_bounds__(512)
void attn_mfma_kernel(const unsigned* __restrict__ q,
                      const unsigned* __restrict__ k,
                      const unsigned* __restrict__ v,
                      float* __restrict__ a)
{
    __shared__ __align__(16) unsigned char Kl[WW*DD*2];      // 32 KiB
    __shared__ __align__(16) unsigned char Vl[DD*WW*2];      // 32 KiB
    __shared__ __align__(16) unsigned short Pl[8][16][40];   // 10 KiB

    const int s  = blockIdx.x;
    const int n  = s & (NHD-1);
    const int bc = s >> 3;
    const int pbase = (bc*(HH/2) + n*(DD/2)) * WW;           // u32 elements
    const unsigned* qg = q + pbase;
    const unsigned* kg = k + pbase;
    const unsigned* vg = v + pbase;
    float* ag = a + (size_t)(bc*HH + n*DD)*WW;

    const int tid = threadIdx.x;

    // --- stage K: thread t -> key = t; 16 d-pair words, native layout ---
    {
        const int key = tid;
        unsigned pk[16];
        #pragma unroll
        for (int dp = 0; dp < 16; ++dp) pk[dp] = kg[(size_t)dp*WW + key];
        #pragma unroll
        for (int j = 0; j < 4; ++j) {
            unsigned off = (unsigned)(key*64 + j*16) ^ ((unsigned)(key&7) << 4);
            *(u32x4*)(Kl + off) = (u32x4){pk[4*j], pk[4*j+1], pk[4*j+2], pk[4*j+3]};
        }
    }
    // --- stage V: unzip d-pairs -> Vl[d][key-pairs] via v_perm ---
    {
        const int dp = tid >> 5;                  // 0..15
        const int k0 = (tid & 31) * 16;
        unsigned rowE[8], rowO[8];
        #pragma unroll
        for (int j = 0; j < 4; ++j) {
            u32x4 U = *(const u32x4*)(vg + (size_t)dp*WW + k0 + 4*j);
            rowE[2*j  ] = __builtin_amdgcn_perm(U[1], U[0], 0x05040100u);
            rowE[2*j+1] = __builtin_amdgcn_perm(U[3], U[2], 0x05040100u);
            rowO[2*j  ] = __builtin_amdgcn_perm(U[1], U[0], 0x07060302u);
            rowO[2*j+1] = __builtin_amdgcn_perm(U[3], U[2], 0x07060302u);
        }
        const int d0 = 2*dp, d1 = 2*dp + 1;
        #pragma unroll
        for (int j16 = 0; j16 < 2; ++j16) {
            unsigned offE = (unsigned)(d0*1024 + k0*2 + j16*16) ^ ((unsigned)(d0&7) << 4);
            unsigned offO = (unsigned)(d1*1024 + k0*2 + j16*16) ^ ((unsigned)(d1&7) << 4);
            *(u32x4*)(Vl + offE) = (u32x4){rowE[4*j16], rowE[4*j16+1], rowE[4*j16+2], rowE[4*j16+3]};
            *(u32x4*)(Vl + offO) = (u32x4){rowO[4*j16], rowO[4*j16+1], rowO[4*j16+2], rowO[4*j16+3]};
        }
    }

    // --- per-wave Q fragments ---
    const int wid  = tid >> 6;
    const int lane = tid & 63;
    const int g = lane >> 4;
    const int r = lane & 15;
    const int w0 = wid * 64;
    const float SC = 0.0625f * 1.44269504088896340736f;  // 1/sqrt(256) * log2(e)

    u32x4 qf[4];
    #pragma unroll
    for (int rf = 0; rf < 4; ++rf) {
        const int row = w0 + rf*16 + r;
        unsigned pq[4];
        #pragma unroll
        for (int jj = 0; jj < 4; ++jj)
            pq[jj] = qg[(size_t)(4*g + jj)*WW + row];
        qf[rf] = (u32x4){pq[0], pq[1], pq[2], pq[3]};
    }

    __syncthreads();   // K/V staged

    f32x4 oacc[4][2];
    float lsum[4][4];
    #pragma unroll
    for (int rf = 0; rf < 4; ++rf) {
        #pragma unroll
        for (int cf = 0; cf < 2; ++cf) oacc[rf][cf] = (f32x4){0.f,0.f,0.f,0.f};
        #pragma unroll
        for (int reg = 0; reg < 4; ++reg) lsum[rf][reg] = 0.f;
    }

    unsigned short* pw = &Pl[wid][0][0];
    const unsigned char* pr = (const unsigned char*)pw;

    #pragma unroll 1
    for (int j0 = 0; j0 < WW; j0 += 32) {
        u32x4 kf[2];
        #pragma unroll
        for (int cf = 0; cf < 2; ++cf) {
            const int key = j0 + cf*16 + r;
            unsigned off = (unsigned)(key*64 + g*16) ^ ((unsigned)(key&7) << 4);
            kf[cf] = *(const u32x4*)(Kl + off);
        }
        u32x4 vf[2];
        #pragma unroll
        for (int cfd = 0; cfd < 2; ++cfd) {
            const int d = r + 16*cfd;
            unsigned off = (unsigned)(d*1024 + (j0 + 8*g)*2) ^ ((unsigned)(d&7) << 4);
            vf[cfd] = *(const u32x4*)(Vl + off);
        }

        f32x4 sacc[4][2];
        #pragma unroll
        for (int rf = 0; rf < 4; ++rf) {
            sacc[rf][0] = mfma16(qf[rf], kf[0], (f32x4){0.f,0.f,0.f,0.f});
            sacc[rf][1] = mfma16(qf[rf], kf[1], (f32x4){0.f,0.f,0.f,0.f});
        }

        #pragma unroll
        for (int rf = 0; rf < 4; ++rf) {
            float p0[4], p1[4];
            #pragma unroll
            for (int reg = 0; reg < 4; ++reg) {
                p0[reg] = exp2f(sacc[rf][0][reg] * SC);
                p1[reg] = exp2f(sacc[rf][1][reg] * SC);
                lsum[rf][reg] += p0[reg] + p1[reg];
            }
            #pragma unroll
            for (int reg = 0; reg < 4; ++reg) {
                pw[(4*g+reg)*40 + r     ] = bf16r(p0[reg]);
                pw[(4*g+reg)*40 + 16 + r] = bf16r(p1[reg]);
            }
            asm volatile("s_waitcnt lgkmcnt(0)" ::: "memory");
            u32x4 pa = *(const u32x4*)(pr + r*80 + g*16);
            oacc[rf][0] = mfma16(pa, vf[0], oacc[rf][0]);
            oacc[rf][1] = mfma16(pa, vf[1], oacc[rf][1]);
        }
    }

    #pragma unroll
    for (int rf = 0; rf < 4; ++rf)
        #pragma unroll
        for (int reg = 0; reg < 4; ++reg) {
            float t = lsum[rf][reg];
            t += __shfl_xor(t, 1);
            t += __shfl_xor(t, 2);
            t += __shfl_xor(t, 4);
            t += __shfl_xor(t, 8);
            lsum[rf][reg] = 1.0f / t;
        }

    #pragma unroll
    for (int rf = 0; rf < 4; ++rf)
        #pragma unroll
        for (int cfd = 0; cfd < 2; ++cfd) {
            const int d = r + 16*cfd;
            f32x4 o = oacc[rf][cfd];
            o[0] *= lsum[rf][0];
            o[1] *= lsum[rf][1];
            o[2] *= lsum[rf][2];
            o[3] *= lsum[rf][3];
            *(f32x4*)(ag + (size_t)d*WW + (w0 + rf*16 + 4*g)) = o;
        }
}

extern "C" void kernel_launch(void* const* d_in, const int* in_sizes, int n_in,
                              void* d_out, int out_size, void* d_ws, size_t ws_size,
                              hipStream_t stream) {
    (void)in_sizes; (void)n_in; (void)out_size; (void)ws_size;
    const float* x  = (const float*)d_in[0];
    const float* wq = (const float*)d_in[1];
    const float* bq = (const float*)d_in[2];
    const float* wk = (const float*)d_in[3];
    const float* bk = (const float*)d_in[4];
    const float* wv = (const float*)d_in[5];
    const float* bv = (const float*)d_in[6];
    const float* wo = (const float*)d_in[7];
    const float* bo = (const float*)d_in[8];
    float* out = (float*)d_out;

    const size_t S = (size_t)BB*CC*HH*WW;          // 8388608
    float*    a    = (float*)d_ws;                 // S fp32
    unsigned* qpk  = (unsigned*)(a + S);           // S/2 u32 each (h-paired bf16)
    unsigned* kpk  = qpk + S/2;
    unsigned* vpk  = kpk + S/2;
    unsigned* wfrag = vpk + S/2;                   // 10240 u32

    wsetup_kernel<<<dim3(4), 64, 0, stream>>>(wq, wk, wv, wo, wfrag);
    dim3 cgrid(WW/32, HH/16, BB);                  // (16,16,4)
    conv_mfma_kernel<3, 0, true ><<<cgrid, 256, 0, stream>>>(
        x, wfrag, bq, bk, bv, qpk, kpk, vpk, nullptr);
    attn_mfma_kernel<<<dim3(512), 512, 0, stream>>>(qpk, kpk, vpk, a);
    conv_mfma_kernel<1, 3, false><<<cgrid, 256, 0, stream>>>(
        a, wfrag, bo, bo, bo, nullptr, nullptr, nullptr, out);
}

// Round 5
// 112.493 us; speedup vs baseline: 6.8602x; 1.0714x over previous
//
#include <hip/hip_runtime.h>

#define BB 4
#define CC 16
#define HH 256
#define WW 512
#define NHD 8
#define DD 32

typedef __attribute__((ext_vector_type(8))) short s8b;        // 8 bf16 (4 VGPRs)
typedef __attribute__((ext_vector_type(4))) float f32x4;
typedef __attribute__((ext_vector_type(4))) unsigned int u32x4;

__device__ inline unsigned cvtpk(float a, float b) {          // (lo=a, hi=b) bf16 RNE
    unsigned r;
    asm("v_cvt_pk_bf16_f32 %0, %1, %2" : "=v"(r) : "v"(a), "v"(b));
    return r;
}
__device__ inline f32x4 mfma16(u32x4 a, u32x4 b, f32x4 c) {
    return __builtin_amdgcn_mfma_f32_16x16x32_bf16(
        __builtin_bit_cast(s8b, a), __builtin_bit_cast(s8b, b), c, 0, 0, 0);
}

// ---------------------------------------------------------------------------
// Setup: build bf16 hi/lo weight A-fragments for all 4 convs (q,k,v,o).
// ---------------------------------------------------------------------------
__global__ __launch_bounds__(64)
void wsetup_kernel(const float* __restrict__ w0, const float* __restrict__ w1,
                   const float* __restrict__ w2, const float* __restrict__ w3,
                   unsigned* __restrict__ wfrag)
{
    const int lane = threadIdx.x;
    const int cv = blockIdx.x;
    const float* wg[4] = {w0, w1, w2, w3};
    const int r = lane & 15, g = lane >> 4;
    const int ci0 = (g & 1) * 8;
    #pragma unroll
    for (int kg = 0; kg < 5; ++kg) {
        int tap = 2*kg + (g >> 1);
        unsigned hi[4], lo[4];
        #pragma unroll
        for (int j = 0; j < 4; ++j) {
            float e0 = 0.f, e1 = 0.f;
            if (tap < 9) {
                e0 = wg[cv][(r*CC + ci0 + 2*j    )*9 + tap];
                e1 = wg[cv][(r*CC + ci0 + 2*j + 1)*9 + tap];
            }
            unsigned h = cvtpk(e0, e1);
            float f0 = __builtin_bit_cast(float, h << 16);
            float f1 = __builtin_bit_cast(float, h & 0xffff0000u);
            hi[j] = h;
            lo[j] = cvtpk(e0 - f0, e1 - f1);
        }
        *(u32x4*)(wfrag + (size_t)(((0*4 + cv)*5 + kg)*64 + lane)*4) =
            (u32x4){hi[0], hi[1], hi[2], hi[3]};
        *(u32x4*)(wfrag + (size_t)(((1*4 + cv)*5 + kg)*64 + lane)*4) =
            (u32x4){lo[0], lo[1], lo[2], lo[3]};
    }
}

// ---------------------------------------------------------------------------
// bf16-MFMA implicit-GEMM 3x3 conv, 3-term split (wh*xh + wl*xh + wh*xl).
// kscale: extra output scale applied to cv==1 (folds softmax scale into k).
// ---------------------------------------------------------------------------
template<int NC, int CVB, bool PAIRED>
__global__ __launch_bounds__(256)
void conv_mfma_kernel(const float* __restrict__ x,
                      const unsigned* __restrict__ wfrag,
                      const float* __restrict__ b0, const float* __restrict__ b1,
                      const float* __restrict__ b2,
                      unsigned* __restrict__ o0, unsigned* __restrict__ o1,
                      unsigned* __restrict__ o2, float* __restrict__ of,
                      float kscale)
{
    constexpr int LC2 = 34, NPX = 18*34;                  // 612 pixels w/ halo
    __shared__ __align__(16) unsigned char xs[NPX*64];

    const int tid = threadIdx.x;
    const int bx = blockIdx.x, by = blockIdx.y, bz = blockIdx.z;
    const int lane = tid & 63, wid = tid >> 6;
    const int g = lane >> 4, r = lane & 15;

    u32x4 wh[NC][5], wl[NC][5];
    #pragma unroll
    for (int cv = 0; cv < NC; ++cv)
        #pragma unroll
        for (int kg = 0; kg < 5; ++kg) {
            wh[cv][kg] = *(const u32x4*)(wfrag + (size_t)(((CVB+cv)*5 + kg)*64 + lane)*4);
            wl[cv][kg] = *(const u32x4*)(wfrag + (size_t)(((4+CVB+cv)*5 + kg)*64 + lane)*4);
        }
    const float* bg[3] = {b0, b1, b2};
    f32x4 bias[NC];
    #pragma unroll
    for (int cv = 0; cv < NC; ++cv) bias[cv] = *(const f32x4*)(bg[cv] + 4*g);

    const int row0 = by*16 - 1, col0 = bx*32 - 1;
    const float* xb = x + (size_t)bz*CC*HH*WW;
    for (int idx = tid; idx < NPX; idx += 256) {
        int rr = idx / LC2, cc2 = idx - rr*LC2;
        int gr = row0 + rr, gc = col0 + cc2;
        bool ok = (gr >= 0) & (gr < HH) & (gc >= 0) & (gc < WW);
        const float* px = xb + (size_t)gr*WW + gc;
        float v0[16];
        #pragma unroll
        for (int c8 = 0; c8 < 16; ++c8) v0[c8] = ok ? px[(size_t)c8*HH*WW] : 0.f;
        unsigned hi[8], lo[8];
        #pragma unroll
        for (int p = 0; p < 8; ++p) {
            unsigned h = cvtpk(v0[2*p], v0[2*p+1]);
            float f0 = __builtin_bit_cast(float, h << 16);
            float f1 = __builtin_bit_cast(float, h & 0xffff0000u);
            hi[p] = h;
            lo[p] = cvtpk(v0[2*p] - f0, v0[2*p+1] - f1);
        }
        unsigned base = (unsigned)idx*64, m = ((unsigned)idx & 3) << 4;
        *(u32x4*)(xs + base + (( 0u) ^ m)) = (u32x4){hi[0], hi[1], hi[2], hi[3]};
        *(u32x4*)(xs + base + ((16u) ^ m)) = (u32x4){hi[4], hi[5], hi[6], hi[7]};
        *(u32x4*)(xs + base + ((32u) ^ m)) = (u32x4){lo[0], lo[1], lo[2], lo[3]};
        *(u32x4*)(xs + base + ((48u) ^ m)) = (u32x4){lo[4], lo[5], lo[6], lo[7]};
    }
    __syncthreads();

    int pk_base[5];
    #pragma unroll
    for (int kg = 0; kg < 5; ++kg) {
        int tap = 2*kg + (g >> 1);
        if (tap > 8) tap = 8;
        pk_base[kg] = (tap/3)*LC2 + (tap%3) + r;
    }
    const unsigned sh = (unsigned)(g & 1) << 4;

    auto tile = [&](int hr, int wt, f32x4* acc) {
        const int tb = hr*LC2 + wt*16;
        #pragma unroll
        for (int kg = 0; kg < 5; ++kg) {
            int px = tb + pk_base[kg];
            unsigned b_ = (unsigned)px*64, m = ((unsigned)px & 3) << 4;
            u32x4 Bh = *(const u32x4*)(xs + b_ + ( sh        ^ m));
            u32x4 Bl = *(const u32x4*)(xs + b_ + ((sh | 32u) ^ m));
            #pragma unroll
            for (int cv = 0; cv < NC; ++cv) {
                acc[cv] = mfma16(wh[cv][kg], Bh, acc[cv]);
                acc[cv] = mfma16(wl[cv][kg], Bh, acc[cv]);
                acc[cv] = mfma16(wh[cv][kg], Bl, acc[cv]);
            }
        }
    };

    #pragma unroll 1
    for (int hp = 0; hp < 2; ++hp) {
        const int hrE = 4*wid + 2*hp;
        #pragma unroll 1
        for (int wt = 0; wt < 2; ++wt) {
            const int col = bx*32 + wt*16 + r;
            if constexpr (PAIRED) {
                f32x4 aE[NC];
                #pragma unroll
                for (int cv = 0; cv < NC; ++cv) aE[cv] = (f32x4){0.f,0.f,0.f,0.f};
                tile(hrE, wt, aE);
                unsigned Ep[NC][2];
                #pragma unroll
                for (int cv = 0; cv < NC; ++cv) {
                    const float sc = (cv == 1) ? kscale : 1.0f;
                    Ep[cv][0] = cvtpk((aE[cv][0] + bias[cv][0])*sc, (aE[cv][1] + bias[cv][1])*sc);
                    Ep[cv][1] = cvtpk((aE[cv][2] + bias[cv][2])*sc, (aE[cv][3] + bias[cv][3])*sc);
                }
                f32x4 aO[NC];
                #pragma unroll
                for (int cv = 0; cv < NC; ++cv) aO[cv] = (f32x4){0.f,0.f,0.f,0.f};
                tile(hrE + 1, wt, aO);
                const int hpix = by*8 + 2*wid + hp;
                #pragma unroll
                for (int cv = 0; cv < NC; ++cv) {
                    const float sc = (cv == 1) ? kscale : 1.0f;
                    unsigned Op0 = cvtpk((aO[cv][0] + bias[cv][0])*sc, (aO[cv][1] + bias[cv][1])*sc);
                    unsigned Op1 = cvtpk((aO[cv][2] + bias[cv][2])*sc, (aO[cv][3] + bias[cv][3])*sc);
                    unsigned wd[4] = {
                        __builtin_amdgcn_perm(Op0, Ep[cv][0], 0x05040100u),
                        __builtin_amdgcn_perm(Op0, Ep[cv][0], 0x07060302u),
                        __builtin_amdgcn_perm(Op1, Ep[cv][1], 0x05040100u),
                        __builtin_amdgcn_perm(Op1, Ep[cv][1], 0x07060302u) };
                    unsigned* op = (cv == 0) ? o0 : (cv == 1) ? o1 : o2;
                    #pragma unroll
                    for (int reg = 0; reg < 4; ++reg)
                        op[((size_t)(bz*CC + 4*g + reg)*(HH/2) + hpix)*WW + col] = wd[reg];
                }
            } else {
                #pragma unroll 1
                for (int e = 0; e < 2; ++e) {
                    f32x4 a0[1] = {(f32x4){0.f,0.f,0.f,0.f}};
                    tile(hrE + e, wt, a0);
                    const int h = by*16 + hrE + e;
                    #pragma unroll
                    for (int reg = 0; reg < 4; ++reg)
                        of[((size_t)(bz*CC + 4*g + reg)*HH + h)*WW + col] =
                            a0[0][reg] + bias[0][reg];
                }
            }
        }
    }
}

// ---------------------------------------------------------------------------
// bf16 MFMA flash attention, swapped-operand form.
// S^T = mfma(K,Q): lane holds one query col (r), keys 4g+reg (+16 per cf).
// P^T built in-register: cvt_pk pairs + 8 ds_bpermute + 4 cndmask per q-frag.
// O^T = mfma(V^T, P^T); l = Sum p via ones-row MFMA (spare accumulator).
// Softmax scale is pre-folded into k by conv<3>; exp2 domain.
// ---------------------------------------------------------------------------
__global__ __launch_bounds__(512)
void attn_mfma_kernel(const unsigned* __restrict__ q,
                      const unsigned* __restrict__ k,
                      const unsigned* __restrict__ v,
                      float* __restrict__ a)
{
    __shared__ __align__(16) unsigned char Kl[WW*DD*2];      // 32 KiB
    __shared__ __align__(16) unsigned char Vl[DD*WW*2];      // 32 KiB

    const int s  = blockIdx.x;
    const int n  = s & (NHD-1);
    const int bc = s >> 3;
    const int pbase = (bc*(HH/2) + n*(DD/2)) * WW;           // u32 elements
    const unsigned* qg = q + pbase;
    const unsigned* kg = k + pbase;
    const unsigned* vg = v + pbase;
    float* ag = a + (size_t)(bc*HH + n*DD)*WW;

    const int tid = threadIdx.x;

    // --- stage K: thread t -> key = t; 16 d-pair words, native layout ---
    {
        const int key = tid;
        unsigned pk[16];
        #pragma unroll
        for (int dp = 0; dp < 16; ++dp) pk[dp] = kg[(size_t)dp*WW + key];
        #pragma unroll
        for (int j = 0; j < 4; ++j) {
            unsigned off = (unsigned)(key*64 + j*16) ^ ((unsigned)(key&7) << 4);
            *(u32x4*)(Kl + off) = (u32x4){pk[4*j], pk[4*j+1], pk[4*j+2], pk[4*j+3]};
        }
    }
    // --- stage V: unzip d-pairs -> Vl[d][key-pairs] via v_perm ---
    {
        const int dp = tid >> 5;                  // 0..15
        const int k0 = (tid & 31) * 16;
        unsigned rowE[8], rowO[8];
        #pragma unroll
        for (int j = 0; j < 4; ++j) {
            u32x4 U = *(const u32x4*)(vg + (size_t)dp*WW + k0 + 4*j);
            rowE[2*j  ] = __builtin_amdgcn_perm(U[1], U[0], 0x05040100u);
            rowE[2*j+1] = __builtin_amdgcn_perm(U[3], U[2], 0x05040100u);
            rowO[2*j  ] = __builtin_amdgcn_perm(U[1], U[0], 0x07060302u);
            rowO[2*j+1] = __builtin_amdgcn_perm(U[3], U[2], 0x07060302u);
        }
        const int d0 = 2*dp, d1 = 2*dp + 1;
        #pragma unroll
        for (int j16 = 0; j16 < 2; ++j16) {
            unsigned offE = (unsigned)(d0*1024 + k0*2 + j16*16) ^ ((unsigned)(d0&7) << 4);
            unsigned offO = (unsigned)(d1*1024 + k0*2 + j16*16) ^ ((unsigned)(d1&7) << 4);
            *(u32x4*)(Vl + offE) = (u32x4){rowE[4*j16], rowE[4*j16+1], rowE[4*j16+2], rowE[4*j16+3]};
            *(u32x4*)(Vl + offO) = (u32x4){rowO[4*j16], rowO[4*j16+1], rowO[4*j16+2], rowO[4*j16+3]};
        }
    }

    const int wid  = tid >> 6;
    const int lane = tid & 63;
    const int g = lane >> 4;
    const int r = lane & 15;
    const int w0 = wid * 64;

    // --- per-wave Q B-fragments (col = query r, k = d octet 8g..8g+7) ---
    u32x4 qf[4];
    #pragma unroll
    for (int rf = 0; rf < 4; ++rf) {
        const int row = w0 + rf*16 + r;
        unsigned pq[4];
        #pragma unroll
        for (int jj = 0; jj < 4; ++jj)
            pq[jj] = qg[(size_t)(4*g + jj)*WW + row];
        qf[rf] = (u32x4){pq[0], pq[1], pq[2], pq[3]};
    }

    __syncthreads();   // K/V staged

    // ones A-fragment (row 0 = 1.0) for l = sum_k P^T
    const u32x4 vones = (r == 0)
        ? (u32x4){0x3F803F80u, 0x3F803F80u, 0x3F803F80u, 0x3F803F80u}
        : (u32x4){0u, 0u, 0u, 0u};
    // bpermute byte-addresses for the fixed P^T redistribution
    const int src0 = ((g & 1)*32 + r) * 4;
    const int src1 = src0 + 64;
    const bool hi2 = (g >= 2);

    f32x4 oacc[4][2];
    f32x4 lacc[4];
    #pragma unroll
    for (int qi = 0; qi < 4; ++qi) {
        oacc[qi][0] = (f32x4){0.f,0.f,0.f,0.f};
        oacc[qi][1] = (f32x4){0.f,0.f,0.f,0.f};
        lacc[qi]    = (f32x4){0.f,0.f,0.f,0.f};
    }

    #pragma unroll 1
    for (int j0 = 0; j0 < WW; j0 += 32) {
        // K A-frags: row = key (r within cf-halftile), k = d octet
        u32x4 kf[2];
        #pragma unroll
        for (int cf = 0; cf < 2; ++cf) {
            const int key = j0 + cf*16 + r;
            unsigned off = (unsigned)(key*64 + g*16) ^ ((unsigned)(key&7) << 4);
            kf[cf] = *(const u32x4*)(Kl + off);
        }
        // V^T A-frags: row = d (r + 16cfd), k = key octet j0+8g..
        u32x4 vf[2];
        #pragma unroll
        for (int cfd = 0; cfd < 2; ++cfd) {
            const int d = r + 16*cfd;
            unsigned off = (unsigned)(d*1024 + (j0 + 8*g)*2) ^ ((unsigned)(d&7) << 4);
            vf[cfd] = *(const u32x4*)(Vl + off);
        }

        // S^T: D row = key(4g+reg), col = query(r)
        f32x4 sacc[4][2];
        #pragma unroll
        for (int qi = 0; qi < 4; ++qi) {
            sacc[qi][0] = mfma16(kf[0], qf[qi], (f32x4){0.f,0.f,0.f,0.f});
            sacc[qi][1] = mfma16(kf[1], qf[qi], (f32x4){0.f,0.f,0.f,0.f});
        }

        #pragma unroll
        for (int qi = 0; qi < 4; ++qi) {
            float p[8];
            #pragma unroll
            for (int reg = 0; reg < 4; ++reg) {
                p[reg]     = exp2f(sacc[qi][0][reg]);
                p[4 + reg] = exp2f(sacc[qi][1][reg]);
            }
            int A = (int)cvtpk(p[0], p[1]);
            int B = (int)cvtpk(p[2], p[3]);
            int C = (int)cvtpk(p[4], p[5]);
            int D = (int)cvtpk(p[6], p[7]);
            int a0 = __builtin_amdgcn_ds_bpermute(src0, A);
            int b0 = __builtin_amdgcn_ds_bpermute(src0, B);
            int c0 = __builtin_amdgcn_ds_bpermute(src0, C);
            int d0 = __builtin_amdgcn_ds_bpermute(src0, D);
            int a1 = __builtin_amdgcn_ds_bpermute(src1, A);
            int b1 = __builtin_amdgcn_ds_bpermute(src1, B);
            int c1 = __builtin_amdgcn_ds_bpermute(src1, C);
            int d1 = __builtin_amdgcn_ds_bpermute(src1, D);
            u32x4 pa = (u32x4){ (unsigned)(hi2 ? c0 : a0),
                                (unsigned)(hi2 ? d0 : b0),
                                (unsigned)(hi2 ? c1 : a1),
                                (unsigned)(hi2 ? d1 : b1) };
            oacc[qi][0] = mfma16(vf[0], pa, oacc[qi][0]);
            oacc[qi][1] = mfma16(vf[1], pa, oacc[qi][1]);
            lacc[qi]    = mfma16(vones, pa, lacc[qi]);
        }
    }

    // normalize + store: O^T row = d(4g+reg + 16cfd), col = query(r)
    #pragma unroll
    for (int qi = 0; qi < 4; ++qi) {
        float l = __shfl(lacc[qi][0], r);     // lane r (g=0) holds row-0 sum
        float inv = 1.0f / l;
        const int qcol = w0 + qi*16 + r;
        #pragma unroll
        for (int cfd = 0; cfd < 2; ++cfd)
            #pragma unroll
            for (int reg = 0; reg < 4; ++reg)
                ag[(size_t)(16*cfd + 4*g + reg)*WW + qcol] =
                    oacc[qi][cfd][reg] * inv;
    }
}

extern "C" void kernel_launch(void* const* d_in, const int* in_sizes, int n_in,
                              void* d_out, int out_size, void* d_ws, size_t ws_size,
                              hipStream_t stream) {
    (void)in_sizes; (void)n_in; (void)out_size; (void)ws_size;
    const float* x  = (const float*)d_in[0];
    const float* wq = (const float*)d_in[1];
    const float* bq = (const float*)d_in[2];
    const float* wk = (const float*)d_in[3];
    const float* bk = (const float*)d_in[4];
    const float* wv = (const float*)d_in[5];
    const float* bv = (const float*)d_in[6];
    const float* wo = (const float*)d_in[7];
    const float* bo = (const float*)d_in[8];
    float* out = (float*)d_out;

    const float SC = 0.0625f * 1.44269504088896340736f;  // 1/sqrt(256) * log2(e)

    const size_t S = (size_t)BB*CC*HH*WW;          // 8388608
    float*    a    = (float*)d_ws;                 // S fp32
    unsigned* qpk  = (unsigned*)(a + S);           // S/2 u32 each (h-paired bf16)
    unsigned* kpk  = qpk + S/2;
    unsigned* vpk  = kpk + S/2;
    unsigned* wfrag = vpk + S/2;                   // 10240 u32

    wsetup_kernel<<<dim3(4), 64, 0, stream>>>(wq, wk, wv, wo, wfrag);
    dim3 cgrid(WW/32, HH/16, BB);                  // (16,16,4)
    conv_mfma_kernel<3, 0, true ><<<cgrid, 256, 0, stream>>>(
        x, wfrag, bq, bk, bv, qpk, kpk, vpk, nullptr, SC);
    attn_mfma_kernel<<<dim3(512), 512, 0, stream>>>(qpk, kpk, vpk, a);
    conv_mfma_kernel<1, 3, false><<<cgrid, 256, 0, stream>>>(
        a, wfrag, bo, bo, bo, nullptr, nullptr, nullptr, out, 1.0f);
}

// Round 6
// 94.031 us; speedup vs baseline: 8.2072x; 1.1963x over previous
//
#include <hip/hip_runtime.h>

#define BB 4
#define CC 16
#define HH 256
#define WW 512
#define NHD 8
#define DD 32

typedef __attribute__((ext_vector_type(8))) short s8b;        // 8 bf16 (4 VGPRs)
typedef __attribute__((ext_vector_type(4))) float f32x4;
typedef __attribute__((ext_vector_type(4))) unsigned int u32x4;
typedef __attribute__((ext_vector_type(2))) int i32x2;

__device__ inline unsigned cvtpk(float a, float b) {          // (lo=a, hi=b) bf16 RNE
    unsigned r;
    asm("v_cvt_pk_bf16_f32 %0, %1, %2" : "=v"(r) : "v"(a), "v"(b));
    return r;
}
__device__ inline f32x4 mfma16(u32x4 a, u32x4 b, f32x4 c) {
    return __builtin_amdgcn_mfma_f32_16x16x32_bf16(
        __builtin_bit_cast(s8b, a), __builtin_bit_cast(s8b, b), c, 0, 0, 0);
}

// ---------------------------------------------------------------------------
// Setup: build bf16 hi/lo weight A-fragments for all 4 convs (q,k,v,o).
// ---------------------------------------------------------------------------
__global__ __launch_bounds__(64)
void wsetup_kernel(const float* __restrict__ w0, const float* __restrict__ w1,
                   const float* __restrict__ w2, const float* __restrict__ w3,
                   unsigned* __restrict__ wfrag)
{
    const int lane = threadIdx.x;
    const int cv = blockIdx.x;
    const float* wg[4] = {w0, w1, w2, w3};
    const int r = lane & 15, g = lane >> 4;
    const int ci0 = (g & 1) * 8;
    #pragma unroll
    for (int kg = 0; kg < 5; ++kg) {
        int tap = 2*kg + (g >> 1);
        unsigned hi[4], lo[4];
        #pragma unroll
        for (int j = 0; j < 4; ++j) {
            float e0 = 0.f, e1 = 0.f;
            if (tap < 9) {
                e0 = wg[cv][(r*CC + ci0 + 2*j    )*9 + tap];
                e1 = wg[cv][(r*CC + ci0 + 2*j + 1)*9 + tap];
            }
            unsigned h = cvtpk(e0, e1);
            float f0 = __builtin_bit_cast(float, h << 16);
            float f1 = __builtin_bit_cast(float, h & 0xffff0000u);
            hi[j] = h;
            lo[j] = cvtpk(e0 - f0, e1 - f1);
        }
        *(u32x4*)(wfrag + (size_t)(((0*4 + cv)*5 + kg)*64 + lane)*4) =
            (u32x4){hi[0], hi[1], hi[2], hi[3]};
        *(u32x4*)(wfrag + (size_t)(((1*4 + cv)*5 + kg)*64 + lane)*4) =
            (u32x4){lo[0], lo[1], lo[2], lo[3]};
    }
}

// ---------------------------------------------------------------------------
// bf16-MFMA implicit-GEMM 3x3 conv, 3-term split (wh*xh + wl*xh + wh*xl).
// kscale: extra output scale applied to cv==1 (folds softmax scale into k).
// ---------------------------------------------------------------------------
template<int NC, int CVB, bool PAIRED>
__global__ __launch_bounds__(256)
void conv_mfma_kernel(const float* __restrict__ x,
                      const unsigned* __restrict__ wfrag,
                      const float* __restrict__ b0, const float* __restrict__ b1,
                      const float* __restrict__ b2,
                      unsigned* __restrict__ o0, unsigned* __restrict__ o1,
                      unsigned* __restrict__ o2, float* __restrict__ of,
                      float kscale)
{
    constexpr int LC2 = 34, NPX = 18*34;                  // 612 pixels w/ halo
    __shared__ __align__(16) unsigned char xs[NPX*64];

    const int tid = threadIdx.x;
    const int bx = blockIdx.x, by = blockIdx.y, bz = blockIdx.z;
    const int lane = tid & 63, wid = tid >> 6;
    const int g = lane >> 4, r = lane & 15;

    u32x4 wh[NC][5], wl[NC][5];
    #pragma unroll
    for (int cv = 0; cv < NC; ++cv)
        #pragma unroll
        for (int kg = 0; kg < 5; ++kg) {
            wh[cv][kg] = *(const u32x4*)(wfrag + (size_t)(((CVB+cv)*5 + kg)*64 + lane)*4);
            wl[cv][kg] = *(const u32x4*)(wfrag + (size_t)(((4+CVB+cv)*5 + kg)*64 + lane)*4);
        }
    const float* bg[3] = {b0, b1, b2};
    f32x4 bias[NC];
    #pragma unroll
    for (int cv = 0; cv < NC; ++cv) bias[cv] = *(const f32x4*)(bg[cv] + 4*g);

    const int row0 = by*16 - 1, col0 = bx*32 - 1;
    const float* xb = x + (size_t)bz*CC*HH*WW;
    for (int idx = tid; idx < NPX; idx += 256) {
        int rr = idx / LC2, cc2 = idx - rr*LC2;
        int gr = row0 + rr, gc = col0 + cc2;
        bool ok = (gr >= 0) & (gr < HH) & (gc >= 0) & (gc < WW);
        const float* px = xb + (size_t)gr*WW + gc;
        float v0[16];
        #pragma unroll
        for (int c8 = 0; c8 < 16; ++c8) v0[c8] = ok ? px[(size_t)c8*HH*WW] : 0.f;
        unsigned hi[8], lo[8];
        #pragma unroll
        for (int p = 0; p < 8; ++p) {
            unsigned h = cvtpk(v0[2*p], v0[2*p+1]);
            float f0 = __builtin_bit_cast(float, h << 16);
            float f1 = __builtin_bit_cast(float, h & 0xffff0000u);
            hi[p] = h;
            lo[p] = cvtpk(v0[2*p] - f0, v0[2*p+1] - f1);
        }
        unsigned base = (unsigned)idx*64, m = ((unsigned)idx & 3) << 4;
        *(u32x4*)(xs + base + (( 0u) ^ m)) = (u32x4){hi[0], hi[1], hi[2], hi[3]};
        *(u32x4*)(xs + base + ((16u) ^ m)) = (u32x4){hi[4], hi[5], hi[6], hi[7]};
        *(u32x4*)(xs + base + ((32u) ^ m)) = (u32x4){lo[0], lo[1], lo[2], lo[3]};
        *(u32x4*)(xs + base + ((48u) ^ m)) = (u32x4){lo[4], lo[5], lo[6], lo[7]};
    }
    __syncthreads();

    int pk_base[5];
    #pragma unroll
    for (int kg = 0; kg < 5; ++kg) {
        int tap = 2*kg + (g >> 1);
        if (tap > 8) tap = 8;
        pk_base[kg] = (tap/3)*LC2 + (tap%3) + r;
    }
    const unsigned sh = (unsigned)(g & 1) << 4;

    auto tile = [&](int hr, int wt, f32x4* acc) {
        const int tb = hr*LC2 + wt*16;
        #pragma unroll
        for (int kg = 0; kg < 5; ++kg) {
            int px = tb + pk_base[kg];
            unsigned b_ = (unsigned)px*64, m = ((unsigned)px & 3) << 4;
            u32x4 Bh = *(const u32x4*)(xs + b_ + ( sh        ^ m));
            u32x4 Bl = *(const u32x4*)(xs + b_ + ((sh | 32u) ^ m));
            #pragma unroll
            for (int cv = 0; cv < NC; ++cv) {
                acc[cv] = mfma16(wh[cv][kg], Bh, acc[cv]);
                acc[cv] = mfma16(wl[cv][kg], Bh, acc[cv]);
                acc[cv] = mfma16(wh[cv][kg], Bl, acc[cv]);
            }
        }
    };

    #pragma unroll 1
    for (int hp = 0; hp < 2; ++hp) {
        const int hrE = 4*wid + 2*hp;
        #pragma unroll 1
        for (int wt = 0; wt < 2; ++wt) {
            const int col = bx*32 + wt*16 + r;
            if constexpr (PAIRED) {
                f32x4 aE[NC];
                #pragma unroll
                for (int cv = 0; cv < NC; ++cv) aE[cv] = (f32x4){0.f,0.f,0.f,0.f};
                tile(hrE, wt, aE);
                unsigned Ep[NC][2];
                #pragma unroll
                for (int cv = 0; cv < NC; ++cv) {
                    const float sc = (cv == 1) ? kscale : 1.0f;
                    Ep[cv][0] = cvtpk((aE[cv][0] + bias[cv][0])*sc, (aE[cv][1] + bias[cv][1])*sc);
                    Ep[cv][1] = cvtpk((aE[cv][2] + bias[cv][2])*sc, (aE[cv][3] + bias[cv][3])*sc);
                }
                f32x4 aO[NC];
                #pragma unroll
                for (int cv = 0; cv < NC; ++cv) aO[cv] = (f32x4){0.f,0.f,0.f,0.f};
                tile(hrE + 1, wt, aO);
                const int hpix = by*8 + 2*wid + hp;
                #pragma unroll
                for (int cv = 0; cv < NC; ++cv) {
                    const float sc = (cv == 1) ? kscale : 1.0f;
                    unsigned Op0 = cvtpk((aO[cv][0] + bias[cv][0])*sc, (aO[cv][1] + bias[cv][1])*sc);
                    unsigned Op1 = cvtpk((aO[cv][2] + bias[cv][2])*sc, (aO[cv][3] + bias[cv][3])*sc);
                    unsigned wd[4] = {
                        __builtin_amdgcn_perm(Op0, Ep[cv][0], 0x05040100u),
                        __builtin_amdgcn_perm(Op0, Ep[cv][0], 0x07060302u),
                        __builtin_amdgcn_perm(Op1, Ep[cv][1], 0x05040100u),
                        __builtin_amdgcn_perm(Op1, Ep[cv][1], 0x07060302u) };
                    unsigned* op = (cv == 0) ? o0 : (cv == 1) ? o1 : o2;
                    #pragma unroll
                    for (int reg = 0; reg < 4; ++reg)
                        op[((size_t)(bz*CC + 4*g + reg)*(HH/2) + hpix)*WW + col] = wd[reg];
                }
            } else {
                #pragma unroll 1
                for (int e = 0; e < 2; ++e) {
                    f32x4 a0[1] = {(f32x4){0.f,0.f,0.f,0.f}};
                    tile(hrE + e, wt, a0);
                    const int h = by*16 + hrE + e;
                    #pragma unroll
                    for (int reg = 0; reg < 4; ++reg)
                        of[((size_t)(bz*CC + 4*g + reg)*HH + h)*WW + col] =
                            a0[0][reg] + bias[0][reg];
                }
            }
        }
    }
}

// ---------------------------------------------------------------------------
// bf16 MFMA flash attention, swapped-operand form, VALU-only P-transpose.
// S^T = mfma(K,Q): lane holds one query col (r), keys 4g+reg (+16 per cf).
// P^T -> B-frag via 4 cvt_pk + 2 v_permlane32_swap (no LDS ops):
//   w0={A.lo,C.lo} w1={B.lo,D.lo} w2={A.hi,C.hi} w3={B.hi,D.hi}
// with PV k-slot->key map = quad perm [0,2,1,3|4,6,5,7], absorbed into the
// V LDS staging word order. l = Sum p via ones-row MFMA.
// Softmax scale pre-folded into k by conv<3>; exp2 domain (raw v_exp_f32).
// ---------------------------------------------------------------------------
__global__ __launch_bounds__(512)
void attn_mfma_kernel(const unsigned* __restrict__ q,
                      const unsigned* __restrict__ k,
                      const unsigned* __restrict__ v,
                      float* __restrict__ a)
{
    __shared__ __align__(16) unsigned char Kl[WW*DD*2];      // 32 KiB
    __shared__ __align__(16) unsigned char Vl[DD*WW*2];      // 32 KiB

    const int s  = blockIdx.x;
    const int n  = s & (NHD-1);
    const int bc = s >> 3;
    const int pbase = (bc*(HH/2) + n*(DD/2)) * WW;           // u32 elements
    const unsigned* qg = q + pbase;
    const unsigned* kg = k + pbase;
    const unsigned* vg = v + pbase;
    float* ag = a + (size_t)(bc*HH + n*DD)*WW;

    const int tid = threadIdx.x;

    // --- stage K: thread t -> key = t; 16 d-pair words, native layout ---
    {
        const int key = tid;
        unsigned pk[16];
        #pragma unroll
        for (int dp = 0; dp < 16; ++dp) pk[dp] = kg[(size_t)dp*WW + key];
        #pragma unroll
        for (int j = 0; j < 4; ++j) {
            unsigned off = (unsigned)(key*64 + j*16) ^ ((unsigned)(key&7) << 4);
            *(u32x4*)(Kl + off) = (u32x4){pk[4*j], pk[4*j+1], pk[4*j+2], pk[4*j+3]};
        }
    }
    // --- stage V: unzip d-pairs -> Vl[d][key-slots] via v_perm.
    // Slot order per 16-key chunk applies quad perm [0,2,1,3]: the two b128
    // writes carry word sets {P0,P1,P4,P5} and {P2,P3,P6,P7}. ---
    {
        const int dp = tid >> 5;                  // 0..15
        const int k0 = (tid & 31) * 16;
        unsigned rowE[8], rowO[8];
        #pragma unroll
        for (int j = 0; j < 4; ++j) {
            u32x4 U = *(const u32x4*)(vg + (size_t)dp*WW + k0 + 4*j);
            rowE[2*j  ] = __builtin_amdgcn_perm(U[1], U[0], 0x05040100u);
            rowE[2*j+1] = __builtin_amdgcn_perm(U[3], U[2], 0x05040100u);
            rowO[2*j  ] = __builtin_amdgcn_perm(U[1], U[0], 0x07060302u);
            rowO[2*j+1] = __builtin_amdgcn_perm(U[3], U[2], 0x07060302u);
        }
        const int d0 = 2*dp, d1 = 2*dp + 1;
        const unsigned bE = (unsigned)(d0*1024 + k0*2);
        const unsigned bO = (unsigned)(d1*1024 + k0*2);
        const unsigned mE = ((unsigned)(d0&7) << 4);
        const unsigned mO = ((unsigned)(d1&7) << 4);
        *(u32x4*)(Vl + ((bE     ) ^ mE)) = (u32x4){rowE[0], rowE[1], rowE[4], rowE[5]};
        *(u32x4*)(Vl + ((bE + 16) ^ mE)) = (u32x4){rowE[2], rowE[3], rowE[6], rowE[7]};
        *(u32x4*)(Vl + ((bO     ) ^ mO)) = (u32x4){rowO[0], rowO[1], rowO[4], rowO[5]};
        *(u32x4*)(Vl + ((bO + 16) ^ mO)) = (u32x4){rowO[2], rowO[3], rowO[6], rowO[7]};
    }

    const int wid  = tid >> 6;
    const int lane = tid & 63;
    const int g = lane >> 4;
    const int r = lane & 15;
    const int w0 = wid * 64;

    // --- per-wave Q B-fragments (col = query r, k = d octet 8g..8g+7) ---
    u32x4 qf[4];
    #pragma unroll
    for (int rf = 0; rf < 4; ++rf) {
        const int row = w0 + rf*16 + r;
        unsigned pq[4];
        #pragma unroll
        for (int jj = 0; jj < 4; ++jj)
            pq[jj] = qg[(size_t)(4*g + jj)*WW + row];
        qf[rf] = (u32x4){pq[0], pq[1], pq[2], pq[3]};
    }

    __syncthreads();   // K/V staged

    // ones A-fragment (row 0 = 1.0) for l = sum_k P^T
    const u32x4 vones = (r == 0)
        ? (u32x4){0x3F803F80u, 0x3F803F80u, 0x3F803F80u, 0x3F803F80u}
        : (u32x4){0u, 0u, 0u, 0u};

    f32x4 oacc[4][2];
    f32x4 lacc[4];
    #pragma unroll
    for (int qi = 0; qi < 4; ++qi) {
        oacc[qi][0] = (f32x4){0.f,0.f,0.f,0.f};
        oacc[qi][1] = (f32x4){0.f,0.f,0.f,0.f};
        lacc[qi]    = (f32x4){0.f,0.f,0.f,0.f};
    }

    #pragma unroll 1
    for (int j0 = 0; j0 < WW; j0 += 32) {
        // K A-frags: row = key (r within cf-halftile), k = d octet
        u32x4 kf[2];
        #pragma unroll
        for (int cf = 0; cf < 2; ++cf) {
            const int key = j0 + cf*16 + r;
            unsigned off = (unsigned)(key*64 + g*16) ^ ((unsigned)(key&7) << 4);
            kf[cf] = *(const u32x4*)(Kl + off);
        }
        // V^T A-frags: row = d (r + 16cfd), k-slots (j0 tile, octet 8g)
        u32x4 vf[2];
        #pragma unroll
        for (int cfd = 0; cfd < 2; ++cfd) {
            const int d = r + 16*cfd;
            unsigned off = (unsigned)(d*1024 + (j0 + 8*g)*2) ^ ((unsigned)(d&7) << 4);
            vf[cfd] = *(const u32x4*)(Vl + off);
        }

        // S^T: D row = key(4g+reg), col = query(r)
        f32x4 sacc[4][2];
        #pragma unroll
        for (int qi = 0; qi < 4; ++qi) {
            sacc[qi][0] = mfma16(kf[0], qf[qi], (f32x4){0.f,0.f,0.f,0.f});
            sacc[qi][1] = mfma16(kf[1], qf[qi], (f32x4){0.f,0.f,0.f,0.f});
        }

        #pragma unroll
        for (int qi = 0; qi < 4; ++qi) {
            float p0 = __builtin_amdgcn_exp2f(sacc[qi][0][0]);
            float p1 = __builtin_amdgcn_exp2f(sacc[qi][0][1]);
            float p2 = __builtin_amdgcn_exp2f(sacc[qi][0][2]);
            float p3 = __builtin_amdgcn_exp2f(sacc[qi][0][3]);
            float p4 = __builtin_amdgcn_exp2f(sacc[qi][1][0]);
            float p5 = __builtin_amdgcn_exp2f(sacc[qi][1][1]);
            float p6 = __builtin_amdgcn_exp2f(sacc[qi][1][2]);
            float p7 = __builtin_amdgcn_exp2f(sacc[qi][1][3]);
            unsigned Aw = cvtpk(p0, p1);   // keys (4g,   4g+1)
            unsigned Bw = cvtpk(p2, p3);   // keys (4g+2, 4g+3)
            unsigned Cw = cvtpk(p4, p5);   // keys (16+4g, 16+4g+1)
            unsigned Dw = cvtpk(p6, p7);   // keys (16+4g+2, 16+4g+3)
            i32x2 w02 = __builtin_amdgcn_permlane32_swap((int)Aw, (int)Cw, false, false);
            i32x2 w13 = __builtin_amdgcn_permlane32_swap((int)Bw, (int)Dw, false, false);
            u32x4 pa = (u32x4){ (unsigned)w02[0], (unsigned)w13[0],
                                (unsigned)w02[1], (unsigned)w13[1] };
            oacc[qi][0] = mfma16(vf[0], pa, oacc[qi][0]);
            oacc[qi][1] = mfma16(vf[1], pa, oacc[qi][1]);
            lacc[qi]    = mfma16(vones, pa, lacc[qi]);
        }
    }

    // normalize + store: O^T row = d(4g+reg + 16cfd), col = query(r)
    #pragma unroll
    for (int qi = 0; qi < 4; ++qi) {
        float l = __shfl(lacc[qi][0], r);     // lane r (g=0,reg0) holds row-0 sum
        float inv = 1.0f / l;
        const int qcol = w0 + qi*16 + r;
        #pragma unroll
        for (int cfd = 0; cfd < 2; ++cfd)
            #pragma unroll
            for (int reg = 0; reg < 4; ++reg)
                ag[(size_t)(16*cfd + 4*g + reg)*WW + qcol] =
                    oacc[qi][cfd][reg] * inv;
    }
}

extern "C" void kernel_launch(void* const* d_in, const int* in_sizes, int n_in,
                              void* d_out, int out_size, void* d_ws, size_t ws_size,
                              hipStream_t stream) {
    (void)in_sizes; (void)n_in; (void)out_size; (void)ws_size;
    const float* x  = (const float*)d_in[0];
    const float* wq = (const float*)d_in[1];
    const float* bq = (const float*)d_in[2];
    const float* wk = (const float*)d_in[3];
    const float* bk = (const float*)d_in[4];
    const float* wv = (const float*)d_in[5];
    const float* bv = (const float*)d_in[6];
    const float* wo = (const float*)d_in[7];
    const float* bo = (const float*)d_in[8];
    float* out = (float*)d_out;

    const float SC = 0.0625f * 1.44269504088896340736f;  // 1/sqrt(256) * log2(e)

    const size_t S = (size_t)BB*CC*HH*WW;          // 8388608
    float*    a    = (float*)d_ws;                 // S fp32
    unsigned* qpk  = (unsigned*)(a + S);           // S/2 u32 each (h-paired bf16)
    unsigned* kpk  = qpk + S/2;
    unsigned* vpk  = kpk + S/2;
    unsigned* wfrag = vpk + S/2;                   // 10240 u32

    wsetup_kernel<<<dim3(4), 64, 0, stream>>>(wq, wk, wv, wo, wfrag);
    dim3 cgrid(WW/32, HH/16, BB);                  // (16,16,4)
    conv_mfma_kernel<3, 0, true ><<<cgrid, 256, 0, stream>>>(
        x, wfrag, bq, bk, bv, qpk, kpk, vpk, nullptr, SC);
    attn_mfma_kernel<<<dim3(512), 512, 0, stream>>>(qpk, kpk, vpk, a);
    conv_mfma_kernel<1, 3, false><<<cgrid, 256, 0, stream>>>(
        a, wfrag, bo, bo, bo, nullptr, nullptr, nullptr, out, 1.0f);
}